// Round 8
// baseline (513.901 us; speedup 1.0000x reference)
//
#include <hip/hip_runtime.h>
#include <hip/hip_bf16.h>
#include <math.h>

#define BATCH 4096
#define HID 256
#define OUT_W 15
#define AK 448   // padded K for obs GEMM (400 valid + 48 zeros)

typedef unsigned short ushort_t;
typedef unsigned int uint_t;

using bf16x8 = __attribute__((ext_vector_type(8))) short;
using f32x4v = __attribute__((ext_vector_type(4))) float;
using f32x2 = __attribute__((ext_vector_type(2))) float;

__device__ __forceinline__ float sigf(float x) { return 1.0f / (1.0f + __expf(-x)); }
__device__ __forceinline__ float tanh_fast(float x) { return 1.0f - 2.0f / (__expf(2.0f * x) + 1.0f); }
__device__ __forceinline__ float bf2f(ushort_t u) { return __uint_as_float(((uint_t)u) << 16); }
__device__ __forceinline__ ushort_t f2bf(float x) {
    uint_t b = __float_as_uint(x);
    return (ushort_t)((b + 0x7fffu + ((b >> 16) & 1u)) >> 16);
}

// ---------------------------------------------------------------------------
// Prep (68 blocks): unchanged from R7.
// ---------------------------------------------------------------------------
__global__ __launch_bounds__(256) void prep_kernel(
    const float* __restrict__ W_ih, const float* __restrict__ W_hh,
    const float* __restrict__ b_ih, const float* __restrict__ b_hh,
    const float* __restrict__ addr_emb, const float* __restrict__ pid_emb,
    const float* __restrict__ sid_emb,
    const float* __restrict__ mlp_w2, const float* __restrict__ mlp_w3,
    const float* __restrict__ conv1_w, const float* __restrict__ conv1_b,
    const float* __restrict__ conv2_w,
    float* __restrict__ W_ih_T, ushort_t* __restrict__ Wb,
    float* __restrict__ bias_all, float* __restrict__ pid_rows,
    float* __restrict__ sid_rows, float* __restrict__ w2t, float* __restrict__ w3t,
    float* __restrict__ w1pp, ushort_t* __restrict__ Btg,
    ushort_t* __restrict__ Wobs_b)
{
    int blk = blockIdx.x, t = threadIdx.x;
    if (blk < 16) {
        // W_ih tile (64 cols j0, k 384..447) -> W_ih_T (WsampT source)
        __shared__ float tile[64][65];
        int j0 = blk * 64;
        int k0 = 384;
        for (int i = t; i < 4096; i += 256) {
            int r = i >> 6, c = i & 63;
            int k = k0 + c;
            tile[r][c] = (k < 432) ? W_ih[(size_t)(j0 + r) * 432 + k] : 0.f;
        }
        __syncthreads();
        for (int i = t; i < 4096; i += 256) {
            int r = i >> 6, c = i & 63;
            int k = k0 + r;
            if (k < 432) W_ih_T[(size_t)k * 1024 + j0 + c] = tile[c][r];
        }
    } else if (blk == 16) {
        const int aids[7] = {0, 1, 4, 2, 3, 5, 6};
        for (int s = 0; s < 7; s++) {
            int aid = aids[s];
            for (int j = t; j < 1024; j += 256) {
                float v = b_ih[j] + b_hh[j];
                #pragma unroll
                for (int k = 0; k < 16; k++)
                    v += addr_emb[aid * 16 + k] * W_ih[(size_t)j * 432 + 416 + k];
                bias_all[s * 1024 + j] = v;
            }
        }
    } else if (blk == 17) {
        for (int p = 0; p < 3; p++)
            for (int j = t; j < 1024; j += 256) {
                float v = 0.f;
                #pragma unroll
                for (int k = 0; k < 16; k++)
                    v += pid_emb[p * 16 + k] * W_ih[(size_t)j * 432 + 400 + k];
                pid_rows[p * 1024 + j] = v;
            }
        for (int p = 0; p < 2; p++)
            for (int j = t; j < 1024; j += 256) {
                float v = 0.f;
                #pragma unroll
                for (int k = 0; k < 16; k++)
                    v += sid_emb[p * 16 + k] * W_ih[(size_t)j * 432 + 400 + k];
                sid_rows[p * 1024 + j] = v;
            }
    } else if (blk == 18) {
        for (int i = t; i < 10000; i += 256) {
            int o = i / 100, k = i % 100;
            w2t[k * 100 + o] = mlp_w2[i];
        }
        for (int i = t; i < 1600; i += 256) {
            int o = i / 100, k = i % 100;
            w3t[k * 16 + o] = mlp_w3[i];
        }
    } else if (blk == 19) {
        // w1pp[icq][i][k][2]: pair halves = ics (icq*8+i, icq*8+4+i)
        for (int i = t; i < 320; i += 256) {
            int half = i & 1, idx = i >> 1;
            int k = idx % 10, pr = idx / 10;
            int icq = pr >> 2, i2 = pr & 3;
            int ic = icq * 8 + i2 + half * 4;
            w1pp[i] = (k < 9) ? conv1_w[ic * 9 + k] : conv1_b[ic];
        }
        for (int i = t; i < 4608; i += 256) {
            int tap = i >> 9;
            int rem = i & 511;
            int oc = rem >> 5, ic = rem & 31;
            Btg[i] = f2bf(conv2_w[(size_t)(oc * 32 + ic) * 9 + tap]);
        }
    } else if (blk < 36) {
        int seg = blk - 20;  // 0..15
        for (int i = seg * 16384 + t; i < (seg + 1) * 16384; i += 256)
            Wb[i] = f2bf(W_hh[i]);
    } else {
        int col0 = (blk - 36) * 32;
        for (int i = t; i < 32 * AK; i += 256) {
            int c = col0 + i / AK, k = i % AK;
            Wobs_b[(size_t)c * AK + k] = (k < 400) ? f2bf(W_ih[(size_t)c * 432 + k]) : (ushort_t)0;
        }
    }
}

// ---------------------------------------------------------------------------
// Conv encoder v8 (unchanged from R7).
// ---------------------------------------------------------------------------
#define CE_RS 640
#define CO_RS 680
#define SM2S 72
#define C2S_CS 324
#define C2S_RS 20
__global__ __launch_bounds__(512, 4) void conv_kernel(
    const float* __restrict__ obs, const float* __restrict__ w1pp,
    const ushort_t* __restrict__ Btg, const float* __restrict__ b2,
    ushort_t* __restrict__ obs_emb_b)
{
    __shared__ __align__(16) ushort_t cE[17 * CE_RS];
    __shared__ __align__(16) ushort_t cO[17 * CO_RS];
    __shared__ __align__(16) float c2s[16 * C2S_CS];
    __shared__ __align__(16) float sm2[33 * SM2S];
    __shared__ __align__(16) float w1s[320];
    const int b = blockIdx.x, t = threadIdx.x;
    const float* og = obs + (size_t)b * 4096;

    const int w = t >> 6, L = t & 63, q = L >> 4, ln = L & 15;

    {
        uint_t* zE = (uint_t*)cE;
        uint_t* zO = (uint_t*)cO;
        for (int i = t; i < CE_RS / 2; i += 512) zE[i] = 0;
        for (int i = t; i < CO_RS / 2; i += 512) zO[i] = 0;
        if (t < 320) {
            int row = (t / 20) + 1, d = t % 20;
            zO[row * (CO_RS / 2) + d] = 0;
        }
    }
    if (t < 80) ((float4*)w1s)[t] = ((const float4*)w1pp)[t];
    if (t < 33) {
        int sw = (t >> 1) & 1;
        sm2[t * SM2S + sw * 4 + 3] = 0.f;
    }

    auto stage_obs = [&](int ph) {
        for (int i = t; i < 33 * 16; i += 512) {
            int row = i >> 4, c4 = i & 15;
            int sw = (row >> 1) & 1;
            int orow = 32 * ph - 1 + row;
            float4 v = float4{0.f, 0.f, 0.f, 0.f};
            if (orow >= 0) v = ((const float4*)(og + (size_t)orow * 64))[c4];
            *(float4*)&sm2[row * SM2S + ((1 + c4) ^ sw) * 4] = v;
        }
    };

    auto conv1_phase = [&](int ph) {
        const int r = t >> 5, g = (t >> 2) & 7, icq = t & 3;
        const int brow = ph ? r : (r + 1);
        float Pt[3][12];
        #pragma unroll
        for (int d = 0; d < 3; d++) {
            int row = 2 * r + d;
            int sw = (row >> 1) & 1;
            const float* base = &sm2[row * SM2S];
            #pragma unroll
            for (int j4 = 0; j4 < 3; j4++) {
                float4 v = *(const float4*)(base + ((2 * g + j4) ^ sw) * 4);
                Pt[d][j4 * 4 + 0] = v.x; Pt[d][j4 * 4 + 1] = v.y;
                Pt[d][j4 * 4 + 2] = v.z; Pt[d][j4 * 4 + 3] = v.w;
            }
        }
        const float* wpbase = &w1s[icq * 80];
        #pragma unroll
        for (int p = 0; p < 4; p++) {
            f32x2 pbc[9];
            #pragma unroll
            for (int d = 0; d < 3; d++)
                #pragma unroll
                for (int dx = 0; dx < 3; dx++) {
                    float v = Pt[d][2 * p + 3 + dx];
                    pbc[d * 3 + dx] = f32x2{v, v};
                }
            f32x2 sall[4];
            #pragma unroll
            for (int i = 0; i < 4; i++) {
                const float* wp = wpbase + i * 20;
                float4 wv0 = *(const float4*)(wp);
                float4 wv1 = *(const float4*)(wp + 4);
                float4 wv2 = *(const float4*)(wp + 8);
                float4 wv3 = *(const float4*)(wp + 12);
                float4 wv4 = *(const float4*)(wp + 16);
                f32x2 W2[10] = {f32x2{wv0.x, wv0.y}, f32x2{wv0.z, wv0.w},
                                f32x2{wv1.x, wv1.y}, f32x2{wv1.z, wv1.w},
                                f32x2{wv2.x, wv2.y}, f32x2{wv2.z, wv2.w},
                                f32x2{wv3.x, wv3.y}, f32x2{wv3.z, wv3.w},
                                f32x2{wv4.x, wv4.y}, f32x2{wv4.z, wv4.w}};
                f32x2 a2 = W2[9];
                #pragma unroll
                for (int k = 0; k < 9; k++)
                    a2 = __builtin_elementwise_fma(pbc[k], W2[k], a2);
                a2 = __builtin_elementwise_max(a2, f32x2{0.f, 0.f});
                sall[i] = a2;
            }
            uint_t d0, d1, d2, d3;
            asm("v_cvt_pk_bf16_f32 %0, %1, %2" : "=v"(d0) : "v"(sall[0].x), "v"(sall[1].x));
            asm("v_cvt_pk_bf16_f32 %0, %1, %2" : "=v"(d1) : "v"(sall[2].x), "v"(sall[3].x));
            asm("v_cvt_pk_bf16_f32 %0, %1, %2" : "=v"(d2) : "v"(sall[0].y), "v"(sall[1].y));
            asm("v_cvt_pk_bf16_f32 %0, %1, %2" : "=v"(d3) : "v"(sall[2].y), "v"(sall[3].y));
            int c = 4 * g + p;
            ushort_t* dst = (c & 1)
                ? &cO[brow * CO_RS + ((c + 1) >> 1) * 40 + icq * 8]
                : &cE[brow * CE_RS + (c >> 1) * 40 + icq * 8];
            *(uint4*)dst = uint4{d0, d1, d2, d3};
        }
    };

    auto conv2_phase = [&](int ph) {
        bf16x8 Bv[9];
        #pragma unroll
        for (int tap = 0; tap < 9; tap++)
            Bv[tap] = *reinterpret_cast<const bf16x8*>(&Btg[(tap * 16 + ln) * 32 + q * 8]);
        const int y = 8 * ph + w;
        f32x4v C = {0.f, 0.f, 0.f, 0.f};
        #pragma unroll
        for (int dy = 0; dy < 3; dy++) {
            int br = 2 * y + dy;
            if (br >= 17) br -= 17;
            bf16x8 a0 = *reinterpret_cast<const bf16x8*>(&cO[br * CO_RS + ln * 40 + q * 8]);
            bf16x8 a1 = *reinterpret_cast<const bf16x8*>(&cE[br * CE_RS + ln * 40 + q * 8]);
            bf16x8 a2 = *reinterpret_cast<const bf16x8*>(&cO[br * CO_RS + (ln + 1) * 40 + q * 8]);
            C = __builtin_amdgcn_mfma_f32_16x16x32_bf16(a0, Bv[dy * 3 + 0], C, 0, 0, 0);
            C = __builtin_amdgcn_mfma_f32_16x16x32_bf16(a1, Bv[dy * 3 + 1], C, 0, 0, 0);
            C = __builtin_amdgcn_mfma_f32_16x16x32_bf16(a2, Bv[dy * 3 + 2], C, 0, 0, 0);
        }
        float bb2 = b2[ln];
        float4 o;
        o.x = fmaxf(C[0] + bb2, 0.f);
        o.y = fmaxf(C[1] + bb2, 0.f);
        o.z = fmaxf(C[2] + bb2, 0.f);
        o.w = fmaxf(C[3] + bb2, 0.f);
        *(float4*)&c2s[ln * C2S_CS + y * C2S_RS + q * 4] = o;
    };

    stage_obs(0);
    __syncthreads();
    conv1_phase(0);
    __syncthreads();
    stage_obs(1);
    conv2_phase(0);
    __syncthreads();
    conv1_phase(1);
    __syncthreads();
    conv2_phase(1);
    __syncthreads();

    ushort_t* ew = (ushort_t*)w1s;
    if (t < 400) {
        int c = t / 25, rem = t % 25, py = rem / 5, px = rem % 5;
        float s = 0.f;
        #pragma unroll
        for (int dy = 0; dy < 3; dy++)
            #pragma unroll
            for (int dx = 0; dx < 3; dx++)
                s += c2s[c * C2S_CS + (3 * py + dy) * C2S_RS + 3 * px + dx];
        ew[t] = f2bf(s * (1.f / 9.f));
    } else if (t < AK) {
        ew[t] = 0;
    }
    __syncthreads();
    if (t < 56)
        ((uint4*)(obs_emb_b + (size_t)b * AK))[t] = ((const uint4*)ew)[t];
}

// ---------------------------------------------------------------------------
// obs_part = obs_emb_b @ Wobs_b.T (MFMA), standard [row][1024] layout.
// ---------------------------------------------------------------------------
__global__ __launch_bounds__(256) void obs_gemm(
    const ushort_t* __restrict__ Ab, const ushort_t* __restrict__ Wob,
    ushort_t* __restrict__ outp)
{
    __shared__ __align__(16) ushort_t As[64 * 72];
    __shared__ __align__(16) ushort_t ob[64 * 132];
    const int t = threadIdx.x;
    const int bm = blockIdx.x & 63, bu = blockIdx.x >> 6;
    const int b0 = bm * 64, n0 = bu * 128;
    const int w = t >> 6, L = t & 63, q = L >> 4, ln = L & 15;
    const int m0 = w * 16;

    f32x4v acc[8];
    #pragma unroll
    for (int i = 0; i < 8; i++) acc[i] = f32x4v{0.f, 0.f, 0.f, 0.f};

    for (int kc = 0; kc < 7; kc++) {
        #pragma unroll
        for (int ii = 0; ii < 2; ii++) {
            int i = t + ii * 256;
            int row = i >> 3, c8 = i & 7;
            *(uint4*)&As[row * 72 + c8 * 8] =
                *(const uint4*)&Ab[(size_t)(b0 + row) * AK + kc * 64 + c8 * 8];
        }
        __syncthreads();
        bf16x8 a[2];
        #pragma unroll
        for (int ks = 0; ks < 2; ks++)
            a[ks] = *reinterpret_cast<const bf16x8*>(&As[(m0 + ln) * 72 + ks * 32 + q * 8]);
        #pragma unroll
        for (int ct = 0; ct < 8; ct++) {
            const ushort_t* wr = Wob + (size_t)(n0 + ct * 16 + ln) * AK + kc * 64 + q * 8;
            bf16x8 bv0 = *reinterpret_cast<const bf16x8*>(wr);
            bf16x8 bv1 = *reinterpret_cast<const bf16x8*>(wr + 32);
            acc[ct] = __builtin_amdgcn_mfma_f32_16x16x32_bf16(a[0], bv0, acc[ct], 0, 0, 0);
            acc[ct] = __builtin_amdgcn_mfma_f32_16x16x32_bf16(a[1], bv1, acc[ct], 0, 0, 0);
        }
        __syncthreads();
    }
    #pragma unroll
    for (int ct = 0; ct < 8; ct++)
        #pragma unroll
        for (int j = 0; j < 4; j++)
            ob[(m0 + q * 4 + j) * 132 + ct * 16 + ln] = f2bf(acc[ct][j]);
    __syncthreads();
    #pragma unroll
    for (int p2 = 0; p2 < 4; p2++) {
        int idx = t + p2 * 256;
        int row = idx >> 4, c8 = idx & 15;
        uint4 v = *(const uint4*)&ob[row * 132 + c8 * 8];
        *(uint4*)&outp[(size_t)(b0 + row) * 1024 + n0 + c8 * 8] = v;
    }
}

// ---------------------------------------------------------------------------
// LSTM chain v2: 512 blocks x 8 rows (2 blocks/CU), 512 thr, ~34 KB LDS.
//   - obs_part read DIRECTLY from global in epilogues (16 KB/block slice,
//     L1-resident) -> no ps_t transpose, no staging phase.
//   - batched heads: wave w owns row w; all 6 pre-rp1 heads (17 dots) in
//     one barrier-free phase via __shfl_xor butterfly reduction.
//   - 11 barriers total (vs ~25 in v1); gemms: g0(shared s1/s1b), s2, s2b,
//     s3b, s4b = 5.
//   hline bufs: 0=h0(->h4b), 1=h1, 2=h1b, 3=h2, 4=h2b, 5=h3b.
//   MFMA uses 16-row A-frag; lanes ln>=8 re-read rows 0-7 (C rows 8-15 are
//   duplicates, ignored: epilogues guard q<2).
// ---------------------------------------------------------------------------
__global__ __launch_bounds__(512, 4) void lstm_chain(
    const ushort_t* __restrict__ obs_part, const float* __restrict__ bias_all,
    const float* __restrict__ pid_rows, const float* __restrict__ sid_rows,
    const int* __restrict__ program_id, const int* __restrict__ shape_id,
    const int* __restrict__ shape_id_0, const int* __restrict__ shape_id_1,
    const ushort_t* __restrict__ Wb, const float* __restrict__ WsampT,
    const float* __restrict__ pid_ext_w, const float* __restrict__ pid_ext_b,
    const float* __restrict__ sid_ext_w, const float* __restrict__ sid_ext_b,
    const float* __restrict__ rp_ext_w, const float* __restrict__ rp_ext_b,
    const float* __restrict__ eps_rp, const float* __restrict__ eps_rp0,
    const float* __restrict__ eps_rp1,
    const float* __restrict__ mlp_w1, const float* __restrict__ mlp_b1,
    const float* __restrict__ w2t, const float* __restrict__ mlp_b2,
    const float* __restrict__ w3t, const float* __restrict__ mlp_b3,
    float* __restrict__ out)
{
    __shared__ __align__(16) ushort_t hline[6 * 8 * 272];  // 26112 B
    __shared__ float z1s[8][102], z2s[8][102];             // 6528 B
    __shared__ float emb_s[8][20];                         // 640 B
    __shared__ float rp0s[8][2];
    __shared__ int sidx_s[4][8];

    const int t = threadIdx.x;
    const int b0 = blockIdx.x * 8;
    const int w = t >> 6, l = t & 63, q = l >> 4, ln = l & 15;
    const int U = w * 32;

    if (t < 32) {
        int tbl = t >> 3, r = t & 7;
        const int* src = (tbl == 0) ? program_id : (tbl == 1) ? shape_id
                       : (tbl == 2) ? shape_id_0 : shape_id_1;
        sidx_s[tbl][r] = src[b0 + r];
    }

    float cA[8], cB[8];      // cell state [j*2+h], valid for q<2
    f32x4v acc[4][2];        // gemm result [gate][h]

    // ---- s0 (bias 0): h=c=0 -> h0 (hline[0]), cA=cB=c0
    if (q < 2) {
        #pragma unroll
        for (int h = 0; h < 2; h++) {
            const int unit = U + h * 16 + ln;
            #pragma unroll
            for (int j = 0; j < 4; j++) {
                int row = q * 4 + j;
                float pre[4];
                #pragma unroll
                for (int g = 0; g < 4; g++) {
                    int col = g * 256 + unit;
                    pre[g] = bf2f(obs_part[(size_t)(b0 + row) * 1024 + col]) + bias_all[col];
                }
                float c2 = sigf(pre[0]) * tanh_fast(pre[2]);
                float hv = sigf(pre[3]) * tanh_fast(c2);
                cA[j * 2 + h] = c2; cB[j * 2 + h] = c2;
                hline[(0 * 8 + row) * 272 + unit] = f2bf(hv);
            }
        }
    }
    __syncthreads();

    auto gemm = [&](int src) {
        bf16x8 a[8];
        #pragma unroll
        for (int kk = 0; kk < 8; kk++)
            a[kk] = *reinterpret_cast<const bf16x8*>(
                &hline[(src * 8 + (ln & 7)) * 272 + kk * 32 + q * 8]);
        #pragma unroll
        for (int g = 0; g < 4; g++)
            #pragma unroll
            for (int h = 0; h < 2; h++) {
                f32x4v z = {0.f, 0.f, 0.f, 0.f};
                const ushort_t* wr = Wb + (size_t)(g * 256 + U + h * 16 + ln) * 256 + q * 8;
                #pragma unroll
                for (int kk = 0; kk < 8; kk++)
                    z = __builtin_amdgcn_mfma_f32_16x16x32_bf16(a[kk],
                        *reinterpret_cast<const bf16x8*>(wr + kk * 32), z, 0, 0, 0);
                acc[g][h] = z;
            }
    };

    auto epi = [&](int bi, const float* samp, int tbl, int dst, float* cr) {
        if (q < 2) {
            #pragma unroll
            for (int h = 0; h < 2; h++) {
                const int unit = U + h * 16 + ln;
                #pragma unroll
                for (int j = 0; j < 4; j++) {
                    int row = q * 4 + j;
                    int si = sidx_s[tbl][row];
                    float pre[4];
                    #pragma unroll
                    for (int g = 0; g < 4; g++) {
                        int col = g * 256 + unit;
                        pre[g] = acc[g][h][j]
                               + bf2f(obs_part[(size_t)(b0 + row) * 1024 + col])
                               + bias_all[bi * 1024 + col]
                               + samp[(size_t)si * 1024 + col];
                    }
                    float c2 = sigf(pre[1]) * cr[j * 2 + h] + sigf(pre[0]) * tanh_fast(pre[2]);
                    float hv = sigf(pre[3]) * tanh_fast(c2);
                    cr[j * 2 + h] = c2;
                    hline[(dst * 8 + row) * 272 + unit] = f2bf(hv);
                }
            }
        }
    };

    // s1 (bias1) + s1b (bias3): shared GEMM from h0
    gemm(0);
    epi(1, pid_rows, 0, 1, cA);    // h1
    epi(3, pid_rows, 0, 2, cB);    // h1b
    __syncthreads();

    // s2 (A path) and s2b (B path): independent, one phase
    gemm(1);
    epi(2, sid_rows, 1, 3, cA);    // h2
    gemm(2);
    epi(4, sid_rows, 2, 4, cB);    // h2b
    __syncthreads();

    // s3b
    gemm(4);
    epi(5, sid_rows, 3, 5, cB);    // h3b
    __syncthreads();

    // ---- batched heads: wave w = row w; 17 dots; shfl butterfly; no barriers
    {
        const int r = w, R = b0 + r, d0 = l * 4;
        float part[17];
        #pragma unroll
        for (int m = 0; m < 17; m++) part[m] = 0.f;
        float hv[4];
        auto ldh = [&](int src) {
            uint2 v = *(const uint2*)&hline[(src * 8 + r) * 272 + d0];
            hv[0] = bf2f((ushort_t)(v.x & 0xffffu)); hv[1] = bf2f((ushort_t)(v.x >> 16));
            hv[2] = bf2f((ushort_t)(v.y & 0xffffu)); hv[3] = bf2f((ushort_t)(v.y >> 16));
        };
        // pid on h0 -> part 0..2
        ldh(0);
        #pragma unroll
        for (int m = 0; m < 3; m++) {
            float4 wv = *(const float4*)&pid_ext_w[m * 256 + d0];
            part[m] += hv[0] * wv.x + hv[1] * wv.y + hv[2] * wv.z + hv[3] * wv.w;
        }
        // sid weights shared by 3 heads
        float4 ws0 = *(const float4*)&sid_ext_w[0 * 256 + d0];
        float4 ws1 = *(const float4*)&sid_ext_w[1 * 256 + d0];
        ldh(1);  // h1 -> sid (3..4)
        part[3] += hv[0]*ws0.x + hv[1]*ws0.y + hv[2]*ws0.z + hv[3]*ws0.w;
        part[4] += hv[0]*ws1.x + hv[1]*ws1.y + hv[2]*ws1.z + hv[3]*ws1.w;
        ldh(2);  // h1b -> sid0 (9..10)
        part[9]  += hv[0]*ws0.x + hv[1]*ws0.y + hv[2]*ws0.z + hv[3]*ws0.w;
        part[10] += hv[0]*ws1.x + hv[1]*ws1.y + hv[2]*ws1.z + hv[3]*ws1.w;
        ldh(4);  // h2b -> sid1 (11..12)
        part[11] += hv[0]*ws0.x + hv[1]*ws0.y + hv[2]*ws0.z + hv[3]*ws0.w;
        part[12] += hv[0]*ws1.x + hv[1]*ws1.y + hv[2]*ws1.z + hv[3]*ws1.w;
        // rp weights shared by 2 heads
        float4 wr0 = *(const float4*)&rp_ext_w[0 * 256 + d0];
        float4 wr1 = *(const float4*)&rp_ext_w[1 * 256 + d0];
        float4 wr2 = *(const float4*)&rp_ext_w[2 * 256 + d0];
        float4 wr3 = *(const float4*)&rp_ext_w[3 * 256 + d0];
        ldh(3);  // h2 -> rp_b0 (5..8)
        part[5] += hv[0]*wr0.x + hv[1]*wr0.y + hv[2]*wr0.z + hv[3]*wr0.w;
        part[6] += hv[0]*wr1.x + hv[1]*wr1.y + hv[2]*wr1.z + hv[3]*wr1.w;
        part[7] += hv[0]*wr2.x + hv[1]*wr2.y + hv[2]*wr2.z + hv[3]*wr2.w;
        part[8] += hv[0]*wr3.x + hv[1]*wr3.y + hv[2]*wr3.z + hv[3]*wr3.w;
        ldh(5);  // h3b -> rp0 (13..16)
        part[13] += hv[0]*wr0.x + hv[1]*wr0.y + hv[2]*wr0.z + hv[3]*wr0.w;
        part[14] += hv[0]*wr1.x + hv[1]*wr1.y + hv[2]*wr1.z + hv[3]*wr1.w;
        part[15] += hv[0]*wr2.x + hv[1]*wr2.y + hv[2]*wr2.z + hv[3]*wr2.w;
        part[16] += hv[0]*wr3.x + hv[1]*wr3.y + hv[2]*wr3.z + hv[3]*wr3.w;
        #pragma unroll
        for (int m = 0; m < 17; m++) {
            float s = part[m];
            s += __shfl_xor(s, 1);  s += __shfl_xor(s, 2);  s += __shfl_xor(s, 4);
            s += __shfl_xor(s, 8);  s += __shfl_xor(s, 16); s += __shfl_xor(s, 32);
            part[m] = s;
        }
        if (l == 0) {
            float* orow = out + (size_t)R * OUT_W;
            orow[0] = part[0] + pid_ext_b[0];
            orow[1] = part[1] + pid_ext_b[1];
            orow[2] = part[2] + pid_ext_b[2];
            orow[3] = part[3] + sid_ext_b[0];
            orow[4] = part[4] + sid_ext_b[1];
            float s0 = part[5] + rp_ext_b[0], s1 = part[6] + rp_ext_b[1];
            float s2 = part[7] + rp_ext_b[2], s3 = part[8] + rp_ext_b[3];
            orow[5] = s0 + __expf(s2) * eps_rp[(size_t)R * 2 + 0];
            orow[6] = s1 + __expf(s3) * eps_rp[(size_t)R * 2 + 1];
            orow[7] = part[9]  + sid_ext_b[0];
            orow[8] = part[10] + sid_ext_b[1];
            orow[9] = part[11] + sid_ext_b[0];
            orow[10] = part[12] + sid_ext_b[1];
            float t0 = part[13] + rp_ext_b[0], t1 = part[14] + rp_ext_b[1];
            float t2 = part[15] + rp_ext_b[2], t3 = part[16] + rp_ext_b[3];
            float v0 = t0 + __expf(t2) * eps_rp0[(size_t)R * 2 + 0];
            float v1 = t1 + __expf(t3) * eps_rp0[(size_t)R * 2 + 1];
            orow[11] = v0; orow[12] = v1;
            rp0s[r][0] = v0; rp0s[r][1] = v1;
        }
    }
    __syncthreads();

    // ---- MLP: rp0 -> 100 -> 100 -> emb (8 rows)
    for (int i = t; i < 800; i += 512) {
        int row = i / 100, j = i % 100;
        z1s[row][j] = tanh_fast(mlp_b1[j] + mlp_w1[j * 2] * rp0s[row][0]
                                          + mlp_w1[j * 2 + 1] * rp0s[row][1]);
    }
    __syncthreads();
    for (int i = t; i < 800; i += 512) {
        int row = i / 100, j = i % 100;
        float s = mlp_b2[j];
        for (int k = 0; k < 100; k++) s += w2t[k * 100 + j] * z1s[row][k];
        z2s[row][j] = tanh_fast(s);
    }
    __syncthreads();
    if (t < 128) {
        int row = t >> 4, o = t & 15;
        float s = mlp_b3[o];
        for (int k = 0; k < 100; k++) s += w3t[k * 16 + o] * z2s[row][k];
        emb_s[row][o] = s;
    }
    __syncthreads();

    // ---- s4b (bias6, samp = emb @ WsampT): h3b -> h4b (hline[0])
    gemm(5);
    if (q < 2) {
        #pragma unroll
        for (int h = 0; h < 2; h++) {
            const int unit = U + h * 16 + ln;
            float pre[4][4];
            #pragma unroll
            for (int j = 0; j < 4; j++) {
                int row = q * 4 + j;
                #pragma unroll
                for (int g = 0; g < 4; g++)
                    pre[g][j] = acc[g][h][j]
                              + bf2f(obs_part[(size_t)(b0 + row) * 1024 + g * 256 + unit])
                              + bias_all[6 * 1024 + g * 256 + unit];
            }
            #pragma unroll
            for (int k = 0; k < 16; k++) {
                float wv[4];
                #pragma unroll
                for (int g = 0; g < 4; g++) wv[g] = WsampT[(size_t)k * 1024 + g * 256 + unit];
                #pragma unroll
                for (int j = 0; j < 4; j++) {
                    float e = emb_s[q * 4 + j][k];
                    #pragma unroll
                    for (int g = 0; g < 4; g++) pre[g][j] += e * wv[g];
                }
            }
            #pragma unroll
            for (int j = 0; j < 4; j++) {
                float ci = cB[j * 2 + h];
                float c2 = sigf(pre[1][j]) * ci + sigf(pre[0][j]) * tanh_fast(pre[2][j]);
                float hv = sigf(pre[3][j]) * tanh_fast(c2);
                hline[(0 * 8 + q * 4 + j) * 272 + unit] = f2bf(hv);
            }
        }
    }
    __syncthreads();

    // ---- rp1 head on h4b -> cols 13..14 (wave per row, butterfly)
    {
        const int r = w, R = b0 + r, d0 = l * 4;
        uint2 v = *(const uint2*)&hline[(0 * 8 + r) * 272 + d0];
        float h0_ = bf2f((ushort_t)(v.x & 0xffffu)), h1_ = bf2f((ushort_t)(v.x >> 16));
        float h2_ = bf2f((ushort_t)(v.y & 0xffffu)), h3_ = bf2f((ushort_t)(v.y >> 16));
        float p[4];
        #pragma unroll
        for (int m = 0; m < 4; m++) {
            float4 wv = *(const float4*)&rp_ext_w[m * 256 + d0];
            p[m] = h0_ * wv.x + h1_ * wv.y + h2_ * wv.z + h3_ * wv.w;
        }
        #pragma unroll
        for (int m = 0; m < 4; m++) {
            float s = p[m];
            s += __shfl_xor(s, 1);  s += __shfl_xor(s, 2);  s += __shfl_xor(s, 4);
            s += __shfl_xor(s, 8);  s += __shfl_xor(s, 16); s += __shfl_xor(s, 32);
            p[m] = s;
        }
        if (l == 0) {
            float s0 = p[0] + rp_ext_b[0], s1 = p[1] + rp_ext_b[1];
            float s2 = p[2] + rp_ext_b[2], s3 = p[3] + rp_ext_b[3];
            out[(size_t)R * OUT_W + 13] = s0 + __expf(s2) * eps_rp1[(size_t)R * 2 + 0];
            out[(size_t)R * OUT_W + 14] = s1 + __expf(s3) * eps_rp1[(size_t)R * 2 + 1];
        }
    }
}

// ---------------------------------------------------------------------------
extern "C" void kernel_launch(void* const* d_in, const int* in_sizes, int n_in,
                              void* d_out, int out_size, void* d_ws, size_t ws_size,
                              hipStream_t stream)
{
    const float* obs        = (const float*)d_in[0];
    const int*   program_id = (const int*)d_in[1];
    const int*   shape_id   = (const int*)d_in[2];
    const int*   shape_id_0 = (const int*)d_in[3];
    const int*   shape_id_1 = (const int*)d_in[4];
    const float* eps_rp     = (const float*)d_in[5];
    const float* eps_rp0    = (const float*)d_in[6];
    const float* eps_rp1    = (const float*)d_in[7];
    const float* conv1_w    = (const float*)d_in[8];
    const float* conv1_b    = (const float*)d_in[9];
    const float* conv2_w    = (const float*)d_in[10];
    const float* conv2_b    = (const float*)d_in[11];
    const float* mlp_w1     = (const float*)d_in[12];
    const float* mlp_b1     = (const float*)d_in[13];
    const float* mlp_w2     = (const float*)d_in[14];
    const float* mlp_b2     = (const float*)d_in[15];
    const float* mlp_w3     = (const float*)d_in[16];
    const float* mlp_b3     = (const float*)d_in[17];
    const float* W_ih       = (const float*)d_in[18];
    const float* b_ih       = (const float*)d_in[19];
    const float* W_hh       = (const float*)d_in[20];
    const float* b_hh       = (const float*)d_in[21];
    const float* addr_emb   = (const float*)d_in[22];
    const float* pid_emb    = (const float*)d_in[23];
    const float* sid_emb    = (const float*)d_in[24];
    const float* pid_ext_w  = (const float*)d_in[25];
    const float* pid_ext_b  = (const float*)d_in[26];
    const float* sid_ext_w  = (const float*)d_in[27];
    const float* sid_ext_b  = (const float*)d_in[28];
    const float* rp_ext_w   = (const float*)d_in[29];
    const float* rp_ext_b   = (const float*)d_in[30];
    float* out = (float*)d_out;

    // workspace layout
    float* ws = (float*)d_ws;
    size_t off = 0;
    float* W_ih_T   = ws + off; off += 432 * 1024;              // fp32 (WsampT source)
    ushort_t* Wb    = (ushort_t*)(ws + off); off += 131072;     // bf16 1024x256
    float* bias_all = ws + off; off += 7 * 1024;
    float* pid_rows = ws + off; off += 3 * 1024;
    float* sid_rows = ws + off; off += 2 * 1024;
    ushort_t* obs_emb_b = (ushort_t*)(ws + off); off += (size_t)BATCH * AK / 2;  // bf16 Bx448
    ushort_t* Wobs_b    = (ushort_t*)(ws + off); off += (size_t)1024 * AK / 2;   // bf16 1024x448
    ushort_t* obs_part = (ushort_t*)(ws + off); off += (size_t)BATCH * 512;      // bf16 Bx1024
    float* w2t = ws + off; off += 10000;
    float* w3t = ws + off; off += 1600;
    float* w1pp = ws + off; off += 384;
    ushort_t* Btg = (ushort_t*)(ws + off); off += 2304;
    float* WsampT = W_ih_T + (size_t)400 * 1024;  // rows 400..415 of W_ih_T

    prep_kernel<<<68, 256, 0, stream>>>(W_ih, W_hh, b_ih, b_hh, addr_emb,
                                        pid_emb, sid_emb, mlp_w2, mlp_w3,
                                        conv1_w, conv1_b, conv2_w,
                                        W_ih_T, Wb, bias_all, pid_rows,
                                        sid_rows, w2t, w3t, w1pp, Btg, Wobs_b);
    conv_kernel<<<BATCH, 512, 0, stream>>>(obs, w1pp, Btg, conv2_b, obs_emb_b);
    obs_gemm<<<512, 256, 0, stream>>>(obs_emb_b, Wobs_b, obs_part);
    lstm_chain<<<512, 512, 0, stream>>>(
        obs_part, bias_all, pid_rows, sid_rows,
        program_id, shape_id, shape_id_0, shape_id_1, Wb, WsampT,
        pid_ext_w, pid_ext_b, sid_ext_w, sid_ext_b, rp_ext_w, rp_ext_b,
        eps_rp, eps_rp0, eps_rp1,
        mlp_w1, mlp_b1, w2t, mlp_b2, w3t, mlp_b3, out);
}

// Round 9
// 415.400 us; speedup vs baseline: 1.2371x; 1.2371x over previous
//
#include <hip/hip_runtime.h>
#include <hip/hip_bf16.h>
#include <math.h>

#define BATCH 4096
#define HID 256
#define OUT_W 15
#define AK 448   // padded K for obs GEMM (400 valid + 48 zeros)

typedef unsigned short ushort_t;
typedef unsigned int uint_t;

using bf16x8 = __attribute__((ext_vector_type(8))) short;
using f32x4v = __attribute__((ext_vector_type(4))) float;
using f32x2 = __attribute__((ext_vector_type(2))) float;

__device__ __forceinline__ float sigf(float x) { return 1.0f / (1.0f + __expf(-x)); }
__device__ __forceinline__ float tanh_fast(float x) { return 1.0f - 2.0f / (__expf(2.0f * x) + 1.0f); }
__device__ __forceinline__ float bf2f(ushort_t u) { return __uint_as_float(((uint_t)u) << 16); }
__device__ __forceinline__ ushort_t f2bf(float x) {
    uint_t b = __float_as_uint(x);
    return (ushort_t)((b + 0x7fffu + ((b >> 16) & 1u)) >> 16);
}

// ---------------------------------------------------------------------------
// Prep (68 blocks): unchanged from R8.
// ---------------------------------------------------------------------------
__global__ __launch_bounds__(256) void prep_kernel(
    const float* __restrict__ W_ih, const float* __restrict__ W_hh,
    const float* __restrict__ b_ih, const float* __restrict__ b_hh,
    const float* __restrict__ addr_emb, const float* __restrict__ pid_emb,
    const float* __restrict__ sid_emb,
    const float* __restrict__ mlp_w2, const float* __restrict__ mlp_w3,
    const float* __restrict__ conv1_w, const float* __restrict__ conv1_b,
    const float* __restrict__ conv2_w,
    float* __restrict__ W_ih_T, ushort_t* __restrict__ Wb,
    float* __restrict__ bias_all, float* __restrict__ pid_rows,
    float* __restrict__ sid_rows, float* __restrict__ w2t, float* __restrict__ w3t,
    float* __restrict__ w1pp, ushort_t* __restrict__ Btg,
    ushort_t* __restrict__ Wobs_b)
{
    int blk = blockIdx.x, t = threadIdx.x;
    if (blk < 16) {
        // W_ih tile (64 cols j0, k 384..447) -> W_ih_T (WsampT source)
        __shared__ float tile[64][65];
        int j0 = blk * 64;
        int k0 = 384;
        for (int i = t; i < 4096; i += 256) {
            int r = i >> 6, c = i & 63;
            int k = k0 + c;
            tile[r][c] = (k < 432) ? W_ih[(size_t)(j0 + r) * 432 + k] : 0.f;
        }
        __syncthreads();
        for (int i = t; i < 4096; i += 256) {
            int r = i >> 6, c = i & 63;
            int k = k0 + r;
            if (k < 432) W_ih_T[(size_t)k * 1024 + j0 + c] = tile[c][r];
        }
    } else if (blk == 16) {
        const int aids[7] = {0, 1, 4, 2, 3, 5, 6};
        for (int s = 0; s < 7; s++) {
            int aid = aids[s];
            for (int j = t; j < 1024; j += 256) {
                float v = b_ih[j] + b_hh[j];
                #pragma unroll
                for (int k = 0; k < 16; k++)
                    v += addr_emb[aid * 16 + k] * W_ih[(size_t)j * 432 + 416 + k];
                bias_all[s * 1024 + j] = v;
            }
        }
    } else if (blk == 17) {
        for (int p = 0; p < 3; p++)
            for (int j = t; j < 1024; j += 256) {
                float v = 0.f;
                #pragma unroll
                for (int k = 0; k < 16; k++)
                    v += pid_emb[p * 16 + k] * W_ih[(size_t)j * 432 + 400 + k];
                pid_rows[p * 1024 + j] = v;
            }
        for (int p = 0; p < 2; p++)
            for (int j = t; j < 1024; j += 256) {
                float v = 0.f;
                #pragma unroll
                for (int k = 0; k < 16; k++)
                    v += sid_emb[p * 16 + k] * W_ih[(size_t)j * 432 + 400 + k];
                sid_rows[p * 1024 + j] = v;
            }
    } else if (blk == 18) {
        for (int i = t; i < 10000; i += 256) {
            int o = i / 100, k = i % 100;
            w2t[k * 100 + o] = mlp_w2[i];
        }
        for (int i = t; i < 1600; i += 256) {
            int o = i / 100, k = i % 100;
            w3t[k * 16 + o] = mlp_w3[i];
        }
    } else if (blk == 19) {
        // w1pp[icq][i][k][2]: pair halves = ics (icq*8+i, icq*8+4+i)
        for (int i = t; i < 320; i += 256) {
            int half = i & 1, idx = i >> 1;
            int k = idx % 10, pr = idx / 10;
            int icq = pr >> 2, i2 = pr & 3;
            int ic = icq * 8 + i2 + half * 4;
            w1pp[i] = (k < 9) ? conv1_w[ic * 9 + k] : conv1_b[ic];
        }
        for (int i = t; i < 4608; i += 256) {
            int tap = i >> 9;
            int rem = i & 511;
            int oc = rem >> 5, ic = rem & 31;
            Btg[i] = f2bf(conv2_w[(size_t)(oc * 32 + ic) * 9 + tap]);
        }
    } else if (blk < 36) {
        int seg = blk - 20;  // 0..15
        for (int i = seg * 16384 + t; i < (seg + 1) * 16384; i += 256)
            Wb[i] = f2bf(W_hh[i]);
    } else {
        int col0 = (blk - 36) * 32;
        for (int i = t; i < 32 * AK; i += 256) {
            int c = col0 + i / AK, k = i % AK;
            Wobs_b[(size_t)c * AK + k] = (k < 400) ? f2bf(W_ih[(size_t)c * 432 + k]) : (ushort_t)0;
        }
    }
}

// ---------------------------------------------------------------------------
// Conv encoder v8 (unchanged from R8).
// ---------------------------------------------------------------------------
#define CE_RS 640
#define CO_RS 680
#define SM2S 72
#define C2S_CS 324
#define C2S_RS 20
__global__ __launch_bounds__(512, 4) void conv_kernel(
    const float* __restrict__ obs, const float* __restrict__ w1pp,
    const ushort_t* __restrict__ Btg, const float* __restrict__ b2,
    ushort_t* __restrict__ obs_emb_b)
{
    __shared__ __align__(16) ushort_t cE[17 * CE_RS];
    __shared__ __align__(16) ushort_t cO[17 * CO_RS];
    __shared__ __align__(16) float c2s[16 * C2S_CS];
    __shared__ __align__(16) float sm2[33 * SM2S];
    __shared__ __align__(16) float w1s[320];
    const int b = blockIdx.x, t = threadIdx.x;
    const float* og = obs + (size_t)b * 4096;

    const int w = t >> 6, L = t & 63, q = L >> 4, ln = L & 15;

    {
        uint_t* zE = (uint_t*)cE;
        uint_t* zO = (uint_t*)cO;
        for (int i = t; i < CE_RS / 2; i += 512) zE[i] = 0;
        for (int i = t; i < CO_RS / 2; i += 512) zO[i] = 0;
        if (t < 320) {
            int row = (t / 20) + 1, d = t % 20;
            zO[row * (CO_RS / 2) + d] = 0;
        }
    }
    if (t < 80) ((float4*)w1s)[t] = ((const float4*)w1pp)[t];
    if (t < 33) {
        int sw = (t >> 1) & 1;
        sm2[t * SM2S + sw * 4 + 3] = 0.f;
    }

    auto stage_obs = [&](int ph) {
        for (int i = t; i < 33 * 16; i += 512) {
            int row = i >> 4, c4 = i & 15;
            int sw = (row >> 1) & 1;
            int orow = 32 * ph - 1 + row;
            float4 v = float4{0.f, 0.f, 0.f, 0.f};
            if (orow >= 0) v = ((const float4*)(og + (size_t)orow * 64))[c4];
            *(float4*)&sm2[row * SM2S + ((1 + c4) ^ sw) * 4] = v;
        }
    };

    auto conv1_phase = [&](int ph) {
        const int r = t >> 5, g = (t >> 2) & 7, icq = t & 3;
        const int brow = ph ? r : (r + 1);
        float Pt[3][12];
        #pragma unroll
        for (int d = 0; d < 3; d++) {
            int row = 2 * r + d;
            int sw = (row >> 1) & 1;
            const float* base = &sm2[row * SM2S];
            #pragma unroll
            for (int j4 = 0; j4 < 3; j4++) {
                float4 v = *(const float4*)(base + ((2 * g + j4) ^ sw) * 4);
                Pt[d][j4 * 4 + 0] = v.x; Pt[d][j4 * 4 + 1] = v.y;
                Pt[d][j4 * 4 + 2] = v.z; Pt[d][j4 * 4 + 3] = v.w;
            }
        }
        const float* wpbase = &w1s[icq * 80];
        #pragma unroll
        for (int p = 0; p < 4; p++) {
            f32x2 pbc[9];
            #pragma unroll
            for (int d = 0; d < 3; d++)
                #pragma unroll
                for (int dx = 0; dx < 3; dx++) {
                    float v = Pt[d][2 * p + 3 + dx];
                    pbc[d * 3 + dx] = f32x2{v, v};
                }
            f32x2 sall[4];
            #pragma unroll
            for (int i = 0; i < 4; i++) {
                const float* wp = wpbase + i * 20;
                float4 wv0 = *(const float4*)(wp);
                float4 wv1 = *(const float4*)(wp + 4);
                float4 wv2 = *(const float4*)(wp + 8);
                float4 wv3 = *(const float4*)(wp + 12);
                float4 wv4 = *(const float4*)(wp + 16);
                f32x2 W2[10] = {f32x2{wv0.x, wv0.y}, f32x2{wv0.z, wv0.w},
                                f32x2{wv1.x, wv1.y}, f32x2{wv1.z, wv1.w},
                                f32x2{wv2.x, wv2.y}, f32x2{wv2.z, wv2.w},
                                f32x2{wv3.x, wv3.y}, f32x2{wv3.z, wv3.w},
                                f32x2{wv4.x, wv4.y}, f32x2{wv4.z, wv4.w}};
                f32x2 a2 = W2[9];
                #pragma unroll
                for (int k = 0; k < 9; k++)
                    a2 = __builtin_elementwise_fma(pbc[k], W2[k], a2);
                a2 = __builtin_elementwise_max(a2, f32x2{0.f, 0.f});
                sall[i] = a2;
            }
            uint_t d0, d1, d2, d3;
            asm("v_cvt_pk_bf16_f32 %0, %1, %2" : "=v"(d0) : "v"(sall[0].x), "v"(sall[1].x));
            asm("v_cvt_pk_bf16_f32 %0, %1, %2" : "=v"(d1) : "v"(sall[2].x), "v"(sall[3].x));
            asm("v_cvt_pk_bf16_f32 %0, %1, %2" : "=v"(d2) : "v"(sall[0].y), "v"(sall[1].y));
            asm("v_cvt_pk_bf16_f32 %0, %1, %2" : "=v"(d3) : "v"(sall[2].y), "v"(sall[3].y));
            int c = 4 * g + p;
            ushort_t* dst = (c & 1)
                ? &cO[brow * CO_RS + ((c + 1) >> 1) * 40 + icq * 8]
                : &cE[brow * CE_RS + (c >> 1) * 40 + icq * 8];
            *(uint4*)dst = uint4{d0, d1, d2, d3};
        }
    };

    auto conv2_phase = [&](int ph) {
        bf16x8 Bv[9];
        #pragma unroll
        for (int tap = 0; tap < 9; tap++)
            Bv[tap] = *reinterpret_cast<const bf16x8*>(&Btg[(tap * 16 + ln) * 32 + q * 8]);
        const int y = 8 * ph + w;
        f32x4v C = {0.f, 0.f, 0.f, 0.f};
        #pragma unroll
        for (int dy = 0; dy < 3; dy++) {
            int br = 2 * y + dy;
            if (br >= 17) br -= 17;
            bf16x8 a0 = *reinterpret_cast<const bf16x8*>(&cO[br * CO_RS + ln * 40 + q * 8]);
            bf16x8 a1 = *reinterpret_cast<const bf16x8*>(&cE[br * CE_RS + ln * 40 + q * 8]);
            bf16x8 a2 = *reinterpret_cast<const bf16x8*>(&cO[br * CO_RS + (ln + 1) * 40 + q * 8]);
            C = __builtin_amdgcn_mfma_f32_16x16x32_bf16(a0, Bv[dy * 3 + 0], C, 0, 0, 0);
            C = __builtin_amdgcn_mfma_f32_16x16x32_bf16(a1, Bv[dy * 3 + 1], C, 0, 0, 0);
            C = __builtin_amdgcn_mfma_f32_16x16x32_bf16(a2, Bv[dy * 3 + 2], C, 0, 0, 0);
        }
        float bb2 = b2[ln];
        float4 o;
        o.x = fmaxf(C[0] + bb2, 0.f);
        o.y = fmaxf(C[1] + bb2, 0.f);
        o.z = fmaxf(C[2] + bb2, 0.f);
        o.w = fmaxf(C[3] + bb2, 0.f);
        *(float4*)&c2s[ln * C2S_CS + y * C2S_RS + q * 4] = o;
    };

    stage_obs(0);
    __syncthreads();
    conv1_phase(0);
    __syncthreads();
    stage_obs(1);
    conv2_phase(0);
    __syncthreads();
    conv1_phase(1);
    __syncthreads();
    conv2_phase(1);
    __syncthreads();

    ushort_t* ew = (ushort_t*)w1s;
    if (t < 400) {
        int c = t / 25, rem = t % 25, py = rem / 5, px = rem % 5;
        float s = 0.f;
        #pragma unroll
        for (int dy = 0; dy < 3; dy++)
            #pragma unroll
            for (int dx = 0; dx < 3; dx++)
                s += c2s[c * C2S_CS + (3 * py + dy) * C2S_RS + 3 * px + dx];
        ew[t] = f2bf(s * (1.f / 9.f));
    } else if (t < AK) {
        ew[t] = 0;
    }
    __syncthreads();
    if (t < 56)
        ((uint4*)(obs_emb_b + (size_t)b * AK))[t] = ((const uint4*)ew)[t];
}

// ---------------------------------------------------------------------------
// obs_part = obs_emb_b @ Wobs_b.T (MFMA), standard [row][1024] layout.
// ---------------------------------------------------------------------------
__global__ __launch_bounds__(256) void obs_gemm(
    const ushort_t* __restrict__ Ab, const ushort_t* __restrict__ Wob,
    ushort_t* __restrict__ outp)
{
    __shared__ __align__(16) ushort_t As[64 * 72];
    __shared__ __align__(16) ushort_t ob[64 * 132];
    const int t = threadIdx.x;
    const int bm = blockIdx.x & 63, bu = blockIdx.x >> 6;
    const int b0 = bm * 64, n0 = bu * 128;
    const int w = t >> 6, L = t & 63, q = L >> 4, ln = L & 15;
    const int m0 = w * 16;

    f32x4v acc[8];
    #pragma unroll
    for (int i = 0; i < 8; i++) acc[i] = f32x4v{0.f, 0.f, 0.f, 0.f};

    for (int kc = 0; kc < 7; kc++) {
        #pragma unroll
        for (int ii = 0; ii < 2; ii++) {
            int i = t + ii * 256;
            int row = i >> 3, c8 = i & 7;
            *(uint4*)&As[row * 72 + c8 * 8] =
                *(const uint4*)&Ab[(size_t)(b0 + row) * AK + kc * 64 + c8 * 8];
        }
        __syncthreads();
        bf16x8 a[2];
        #pragma unroll
        for (int ks = 0; ks < 2; ks++)
            a[ks] = *reinterpret_cast<const bf16x8*>(&As[(m0 + ln) * 72 + ks * 32 + q * 8]);
        #pragma unroll
        for (int ct = 0; ct < 8; ct++) {
            const ushort_t* wr = Wob + (size_t)(n0 + ct * 16 + ln) * AK + kc * 64 + q * 8;
            bf16x8 bv0 = *reinterpret_cast<const bf16x8*>(wr);
            bf16x8 bv1 = *reinterpret_cast<const bf16x8*>(wr + 32);
            acc[ct] = __builtin_amdgcn_mfma_f32_16x16x32_bf16(a[0], bv0, acc[ct], 0, 0, 0);
            acc[ct] = __builtin_amdgcn_mfma_f32_16x16x32_bf16(a[1], bv1, acc[ct], 0, 0, 0);
        }
        __syncthreads();
    }
    #pragma unroll
    for (int ct = 0; ct < 8; ct++)
        #pragma unroll
        for (int j = 0; j < 4; j++)
            ob[(m0 + q * 4 + j) * 132 + ct * 16 + ln] = f2bf(acc[ct][j]);
    __syncthreads();
    #pragma unroll
    for (int p2 = 0; p2 < 4; p2++) {
        int idx = t + p2 * 256;
        int row = idx >> 4, c8 = idx & 15;
        uint4 v = *(const uint4*)&ob[row * 132 + c8 * 8];
        *(uint4*)&outp[(size_t)(b0 + row) * 1024 + n0 + c8 * 8] = v;
    }
}

// ---------------------------------------------------------------------------
// LSTM chain v3: dual-path-packed 16-row MFMA, spill-free at (512,4).
//   512 blocks x 8 batch rows; hline rows 0-7 = path A state, 8-15 = path B.
//   One GEMM phase computes BOTH paths (lane path = q>>1): phases =
//   g(h0)[s1+s1b], g(h1|h1b)[s2+s2b], g(h2b)[s3b], g(h3b)[s4b] -> 4 GEMMs.
//   Per-h gemm+epi split keeps acc[4] (16 VGPR): peak ~90-100 VGPR < 128 cap.
//   obs_part slice staged to LDS once (coalesced); hline stride 264 ushorts
//   (132 dw = 4 mod 32 -> free 2-way on ds_read_b128 A-frags).
// ---------------------------------------------------------------------------
#define HLS 264   // hline row stride (ushorts)
__global__ __launch_bounds__(512, 4) void lstm_chain(
    const ushort_t* __restrict__ obs_part, const float* __restrict__ bias_all,
    const float* __restrict__ pid_rows, const float* __restrict__ sid_rows,
    const int* __restrict__ program_id, const int* __restrict__ shape_id,
    const int* __restrict__ shape_id_0, const int* __restrict__ shape_id_1,
    const ushort_t* __restrict__ Wb, const float* __restrict__ WsampT,
    const float* __restrict__ pid_ext_w, const float* __restrict__ pid_ext_b,
    const float* __restrict__ sid_ext_w, const float* __restrict__ sid_ext_b,
    const float* __restrict__ rp_ext_w, const float* __restrict__ rp_ext_b,
    const float* __restrict__ eps_rp, const float* __restrict__ eps_rp0,
    const float* __restrict__ eps_rp1,
    const float* __restrict__ mlp_w1, const float* __restrict__ mlp_b1,
    const float* __restrict__ w2t, const float* __restrict__ mlp_b2,
    const float* __restrict__ w3t, const float* __restrict__ mlp_b3,
    float* __restrict__ out)
{
    __shared__ __align__(16) ushort_t hline[4][16 * HLS];  // 33792 B
    __shared__ __align__(16) ushort_t ps[8 * 1032];        // 16512 B
    __shared__ float z1s[8][102], z2s[8][102];             // 6528 B
    __shared__ float emb_s[8][20];                         // 640 B
    __shared__ float rp0s[8][2];
    __shared__ int sidx_s[4][8];

    const int t = threadIdx.x;
    const int b0 = blockIdx.x * 8;
    const int w = t >> 6, l = t & 63, q = l >> 4, ln = l & 15;
    const int U = w * 32;
    const int path = q >> 1;   // 0 = A chain, 1 = B chain

    if (t < 32) {
        int tbl = t >> 3, r = t & 7;
        const int* src = (tbl == 0) ? program_id : (tbl == 1) ? shape_id
                       : (tbl == 2) ? shape_id_0 : shape_id_1;
        sidx_s[tbl][r] = src[b0 + r];
    }
    // stage obs_part slice (8 rows x 1024 bf16), coalesced
    for (int i = t; i < 1024; i += 512) {
        int r = i >> 7, c8 = i & 127;
        uint4 v = *(const uint4*)&obs_part[(size_t)(b0 + r) * 1024 + c8 * 8];
        *(uint4*)&ps[r * 1032 + c8 * 8] = v;
    }
    // zero buf3 rows 0-7 (A half unused; read by s4b gemm)
    for (int i = t; i < 8 * HLS / 2; i += 512)
        ((uint_t*)&hline[3][0])[i] = 0;
    __syncthreads();

    float c8v[8];   // cell state [j*2+h] for this thread's (path, rows, units)

    // ---- s0 (bias 0): h=c=0 -> h0 in buf0 rows 0-15 (both halves identical)
    #pragma unroll
    for (int h = 0; h < 2; h++) {
        const int unit = U + h * 16 + ln;
        #pragma unroll
        for (int j = 0; j < 4; j++) {
            int rr = q * 4 + j, r8 = rr & 7;
            float pre[4];
            #pragma unroll
            for (int g = 0; g < 4; g++) {
                int col = g * 256 + unit;
                pre[g] = bf2f(ps[r8 * 1032 + col]) + bias_all[col];
            }
            float c2 = sigf(pre[0]) * tanh_fast(pre[2]);
            float hv = sigf(pre[3]) * tanh_fast(c2);
            c8v[j * 2 + h] = c2;
            hline[0][rr * HLS + unit] = f2bf(hv);
        }
    }
    __syncthreads();

    // phase: gemm(src 16 rows) + dual-path epilogue -> dst
    auto phase = [&](int src, int dst, int biA, int biB,
                     const float* samp, int tblA, int tblB, bool doA) {
        bf16x8 a[8];
        #pragma unroll
        for (int kk = 0; kk < 8; kk++)
            a[kk] = *reinterpret_cast<const bf16x8*>(
                &hline[src][ln * HLS + kk * 32 + q * 8]);
        const int bi = path ? biB : biA;
        const int tbl = path ? tblB : tblA;
        const float* biasp = bias_all + bi * 1024;
        #pragma unroll
        for (int h = 0; h < 2; h++) {
            const int unit = U + h * 16 + ln;
            f32x4v acc[4];
            #pragma unroll
            for (int g = 0; g < 4; g++) {
                f32x4v z = {0.f, 0.f, 0.f, 0.f};
                const ushort_t* wr = Wb + (size_t)(g * 256 + unit) * 256 + q * 8;
                #pragma unroll
                for (int kk = 0; kk < 8; kk++)
                    z = __builtin_amdgcn_mfma_f32_16x16x32_bf16(a[kk],
                        *reinterpret_cast<const bf16x8*>(wr + kk * 32), z, 0, 0, 0);
                acc[g] = z;
            }
            if (doA || path) {
                #pragma unroll
                for (int j = 0; j < 4; j++) {
                    int rr = q * 4 + j, r8 = rr & 7;
                    int si = sidx_s[tbl][r8];
                    float pre[4];
                    #pragma unroll
                    for (int g = 0; g < 4; g++) {
                        int col = g * 256 + unit;
                        pre[g] = acc[g][j] + bf2f(ps[r8 * 1032 + col]) + biasp[col]
                               + samp[(size_t)si * 1024 + col];
                    }
                    float c2 = sigf(pre[1]) * c8v[j * 2 + h] + sigf(pre[0]) * tanh_fast(pre[2]);
                    float hv = sigf(pre[3]) * tanh_fast(c2);
                    c8v[j * 2 + h] = c2;
                    hline[dst][rr * HLS + unit] = f2bf(hv);
                }
            }
        }
    };

    // phase 1: s1 (bias1) + s1b (bias3), both pid samp -> buf1 (h1 | h1b)
    phase(0, 1, 1, 3, pid_rows, 0, 0, true);
    __syncthreads();
    // phase 2: s2 (bias2, sid[shape_id]) + s2b (bias4, sid[shape_id_0]) -> buf2
    phase(1, 2, 2, 4, sid_rows, 1, 2, true);
    __syncthreads();
    // phase 3: s3b only (bias5, sid[shape_id_1]) -> buf3 rows 8-15
    phase(2, 3, 5, 5, sid_rows, 3, 3, false);
    __syncthreads();

    // ---- batched heads: wave w = row w; 17 dots; shfl butterfly
    {
        const int r = w, R = b0 + r, d0 = l * 4;
        float part[17];
        #pragma unroll
        for (int m = 0; m < 17; m++) part[m] = 0.f;
        float hv[4];
        auto ldh = [&](int buf, int half) {
            uint2 v = *(const uint2*)&hline[buf][(r + half * 8) * HLS + d0];
            hv[0] = bf2f((ushort_t)(v.x & 0xffffu)); hv[1] = bf2f((ushort_t)(v.x >> 16));
            hv[2] = bf2f((ushort_t)(v.y & 0xffffu)); hv[3] = bf2f((ushort_t)(v.y >> 16));
        };
        // pid on h0 -> part 0..2
        ldh(0, 0);
        #pragma unroll
        for (int m = 0; m < 3; m++) {
            float4 wv = *(const float4*)&pid_ext_w[m * 256 + d0];
            part[m] += hv[0] * wv.x + hv[1] * wv.y + hv[2] * wv.z + hv[3] * wv.w;
        }
        float4 ws0 = *(const float4*)&sid_ext_w[0 * 256 + d0];
        float4 ws1 = *(const float4*)&sid_ext_w[1 * 256 + d0];
        ldh(1, 0);  // h1 -> sid (3..4)
        part[3] += hv[0]*ws0.x + hv[1]*ws0.y + hv[2]*ws0.z + hv[3]*ws0.w;
        part[4] += hv[0]*ws1.x + hv[1]*ws1.y + hv[2]*ws1.z + hv[3]*ws1.w;
        ldh(1, 1);  // h1b -> sid0 (9..10)
        part[9]  += hv[0]*ws0.x + hv[1]*ws0.y + hv[2]*ws0.z + hv[3]*ws0.w;
        part[10] += hv[0]*ws1.x + hv[1]*ws1.y + hv[2]*ws1.z + hv[3]*ws1.w;
        ldh(2, 1);  // h2b -> sid1 (11..12)
        part[11] += hv[0]*ws0.x + hv[1]*ws0.y + hv[2]*ws0.z + hv[3]*ws0.w;
        part[12] += hv[0]*ws1.x + hv[1]*ws1.y + hv[2]*ws1.z + hv[3]*ws1.w;
        float4 wr0 = *(const float4*)&rp_ext_w[0 * 256 + d0];
        float4 wr1 = *(const float4*)&rp_ext_w[1 * 256 + d0];
        float4 wr2 = *(const float4*)&rp_ext_w[2 * 256 + d0];
        float4 wr3 = *(const float4*)&rp_ext_w[3 * 256 + d0];
        ldh(2, 0);  // h2 -> rp_b0 (5..8)
        part[5] += hv[0]*wr0.x + hv[1]*wr0.y + hv[2]*wr0.z + hv[3]*wr0.w;
        part[6] += hv[0]*wr1.x + hv[1]*wr1.y + hv[2]*wr1.z + hv[3]*wr1.w;
        part[7] += hv[0]*wr2.x + hv[1]*wr2.y + hv[2]*wr2.z + hv[3]*wr2.w;
        part[8] += hv[0]*wr3.x + hv[1]*wr3.y + hv[2]*wr3.z + hv[3]*wr3.w;
        ldh(3, 1);  // h3b -> rp0 (13..16)
        part[13] += hv[0]*wr0.x + hv[1]*wr0.y + hv[2]*wr0.z + hv[3]*wr0.w;
        part[14] += hv[0]*wr1.x + hv[1]*wr1.y + hv[2]*wr1.z + hv[3]*wr1.w;
        part[15] += hv[0]*wr2.x + hv[1]*wr2.y + hv[2]*wr2.z + hv[3]*wr2.w;
        part[16] += hv[0]*wr3.x + hv[1]*wr3.y + hv[2]*wr3.z + hv[3]*wr3.w;
        #pragma unroll
        for (int m = 0; m < 17; m++) {
            float s = part[m];
            s += __shfl_xor(s, 1);  s += __shfl_xor(s, 2);  s += __shfl_xor(s, 4);
            s += __shfl_xor(s, 8);  s += __shfl_xor(s, 16); s += __shfl_xor(s, 32);
            part[m] = s;
        }
        if (l == 0) {
            float* orow = out + (size_t)R * OUT_W;
            orow[0] = part[0] + pid_ext_b[0];
            orow[1] = part[1] + pid_ext_b[1];
            orow[2] = part[2] + pid_ext_b[2];
            orow[3] = part[3] + sid_ext_b[0];
            orow[4] = part[4] + sid_ext_b[1];
            float s0 = part[5] + rp_ext_b[0], s1 = part[6] + rp_ext_b[1];
            float s2 = part[7] + rp_ext_b[2], s3 = part[8] + rp_ext_b[3];
            orow[5] = s0 + __expf(s2) * eps_rp[(size_t)R * 2 + 0];
            orow[6] = s1 + __expf(s3) * eps_rp[(size_t)R * 2 + 1];
            orow[7] = part[9]  + sid_ext_b[0];
            orow[8] = part[10] + sid_ext_b[1];
            orow[9] = part[11] + sid_ext_b[0];
            orow[10] = part[12] + sid_ext_b[1];
            float t0 = part[13] + rp_ext_b[0], t1 = part[14] + rp_ext_b[1];
            float t2 = part[15] + rp_ext_b[2], t3 = part[16] + rp_ext_b[3];
            float v0 = t0 + __expf(t2) * eps_rp0[(size_t)R * 2 + 0];
            float v1 = t1 + __expf(t3) * eps_rp0[(size_t)R * 2 + 1];
            orow[11] = v0; orow[12] = v1;
            rp0s[r][0] = v0; rp0s[r][1] = v1;
        }
    }
    __syncthreads();

    // ---- MLP: rp0 -> 100 -> 100 -> emb (8 rows)
    for (int i = t; i < 800; i += 512) {
        int row = i / 100, j = i % 100;
        z1s[row][j] = tanh_fast(mlp_b1[j] + mlp_w1[j * 2] * rp0s[row][0]
                                          + mlp_w1[j * 2 + 1] * rp0s[row][1]);
    }
    __syncthreads();
    for (int i = t; i < 800; i += 512) {
        int row = i / 100, j = i % 100;
        float s = mlp_b2[j];
        for (int k = 0; k < 100; k++) s += w2t[k * 100 + j] * z1s[row][k];
        z2s[row][j] = tanh_fast(s);
    }
    __syncthreads();
    if (t < 128) {
        int row = t >> 4, o = t & 15;
        float s = mlp_b3[o];
        for (int k = 0; k < 100; k++) s += w3t[k * 16 + o] * z2s[row][k];
        emb_s[row][o] = s;
    }
    __syncthreads();

    // ---- s4b (bias6, samp = emb @ WsampT): gemm(buf3) B half -> buf0 rows 8-15
    {
        bf16x8 a[8];
        #pragma unroll
        for (int kk = 0; kk < 8; kk++)
            a[kk] = *reinterpret_cast<const bf16x8*>(
                &hline[3][ln * HLS + kk * 32 + q * 8]);
        #pragma unroll
        for (int h = 0; h < 2; h++) {
            const int unit = U + h * 16 + ln;
            f32x4v acc[4];
            #pragma unroll
            for (int g = 0; g < 4; g++) {
                f32x4v z = {0.f, 0.f, 0.f, 0.f};
                const ushort_t* wr = Wb + (size_t)(g * 256 + unit) * 256 + q * 8;
                #pragma unroll
                for (int kk = 0; kk < 8; kk++)
                    z = __builtin_amdgcn_mfma_f32_16x16x32_bf16(a[kk],
                        *reinterpret_cast<const bf16x8*>(wr + kk * 32), z, 0, 0, 0);
                acc[g] = z;
            }
            if (path) {
                float pre[4][4];
                #pragma unroll
                for (int j = 0; j < 4; j++) {
                    int r8 = (q * 4 + j) & 7;
                    #pragma unroll
                    for (int g = 0; g < 4; g++) {
                        int col = g * 256 + unit;
                        pre[g][j] = acc[g][j] + bf2f(ps[r8 * 1032 + col])
                                  + bias_all[6 * 1024 + col];
                    }
                }
                #pragma unroll
                for (int k = 0; k < 16; k++) {
                    float wv[4];
                    #pragma unroll
                    for (int g = 0; g < 4; g++)
                        wv[g] = WsampT[(size_t)k * 1024 + g * 256 + unit];
                    #pragma unroll
                    for (int j = 0; j < 4; j++) {
                        float e = emb_s[(q * 4 + j) & 7][k];
                        #pragma unroll
                        for (int g = 0; g < 4; g++) pre[g][j] += e * wv[g];
                    }
                }
                #pragma unroll
                for (int j = 0; j < 4; j++) {
                    float c2 = sigf(pre[1][j]) * c8v[j * 2 + h]
                             + sigf(pre[0][j]) * tanh_fast(pre[2][j]);
                    float hv = sigf(pre[3][j]) * tanh_fast(c2);
                    hline[0][(q * 4 + j) * HLS + unit] = f2bf(hv);
                }
            }
        }
    }
    __syncthreads();

    // ---- rp1 head on h4b (buf0 rows 8-15)
    {
        const int r = w, R = b0 + r, d0 = l * 4;
        uint2 v = *(const uint2*)&hline[0][(r + 8) * HLS + d0];
        float h0_ = bf2f((ushort_t)(v.x & 0xffffu)), h1_ = bf2f((ushort_t)(v.x >> 16));
        float h2_ = bf2f((ushort_t)(v.y & 0xffffu)), h3_ = bf2f((ushort_t)(v.y >> 16));
        float p[4];
        #pragma unroll
        for (int m = 0; m < 4; m++) {
            float4 wv = *(const float4*)&rp_ext_w[m * 256 + d0];
            p[m] = h0_ * wv.x + h1_ * wv.y + h2_ * wv.z + h3_ * wv.w;
        }
        #pragma unroll
        for (int m = 0; m < 4; m++) {
            float s = p[m];
            s += __shfl_xor(s, 1);  s += __shfl_xor(s, 2);  s += __shfl_xor(s, 4);
            s += __shfl_xor(s, 8);  s += __shfl_xor(s, 16); s += __shfl_xor(s, 32);
            p[m] = s;
        }
        if (l == 0) {
            float s0 = p[0] + rp_ext_b[0], s1 = p[1] + rp_ext_b[1];
            float s2 = p[2] + rp_ext_b[2], s3 = p[3] + rp_ext_b[3];
            out[(size_t)R * OUT_W + 13] = s0 + __expf(s2) * eps_rp1[(size_t)R * 2 + 0];
            out[(size_t)R * OUT_W + 14] = s1 + __expf(s3) * eps_rp1[(size_t)R * 2 + 1];
        }
    }
}

// ---------------------------------------------------------------------------
extern "C" void kernel_launch(void* const* d_in, const int* in_sizes, int n_in,
                              void* d_out, int out_size, void* d_ws, size_t ws_size,
                              hipStream_t stream)
{
    const float* obs        = (const float*)d_in[0];
    const int*   program_id = (const int*)d_in[1];
    const int*   shape_id   = (const int*)d_in[2];
    const int*   shape_id_0 = (const int*)d_in[3];
    const int*   shape_id_1 = (const int*)d_in[4];
    const float* eps_rp     = (const float*)d_in[5];
    const float* eps_rp0    = (const float*)d_in[6];
    const float* eps_rp1    = (const float*)d_in[7];
    const float* conv1_w    = (const float*)d_in[8];
    const float* conv1_b    = (const float*)d_in[9];
    const float* conv2_w    = (const float*)d_in[10];
    const float* conv2_b    = (const float*)d_in[11];
    const float* mlp_w1     = (const float*)d_in[12];
    const float* mlp_b1     = (const float*)d_in[13];
    const float* mlp_w2     = (const float*)d_in[14];
    const float* mlp_b2     = (const float*)d_in[15];
    const float* mlp_w3     = (const float*)d_in[16];
    const float* mlp_b3     = (const float*)d_in[17];
    const float* W_ih       = (const float*)d_in[18];
    const float* b_ih       = (const float*)d_in[19];
    const float* W_hh       = (const float*)d_in[20];
    const float* b_hh       = (const float*)d_in[21];
    const float* addr_emb   = (const float*)d_in[22];
    const float* pid_emb    = (const float*)d_in[23];
    const float* sid_emb    = (const float*)d_in[24];
    const float* pid_ext_w  = (const float*)d_in[25];
    const float* pid_ext_b  = (const float*)d_in[26];
    const float* sid_ext_w  = (const float*)d_in[27];
    const float* sid_ext_b  = (const float*)d_in[28];
    const float* rp_ext_w   = (const float*)d_in[29];
    const float* rp_ext_b   = (const float*)d_in[30];
    float* out = (float*)d_out;

    // workspace layout
    float* ws = (float*)d_ws;
    size_t off = 0;
    float* W_ih_T   = ws + off; off += 432 * 1024;              // fp32 (WsampT source)
    ushort_t* Wb    = (ushort_t*)(ws + off); off += 131072;     // bf16 1024x256
    float* bias_all = ws + off; off += 7 * 1024;
    float* pid_rows = ws + off; off += 3 * 1024;
    float* sid_rows = ws + off; off += 2 * 1024;
    ushort_t* obs_emb_b = (ushort_t*)(ws + off); off += (size_t)BATCH * AK / 2;  // bf16 Bx448
    ushort_t* Wobs_b    = (ushort_t*)(ws + off); off += (size_t)1024 * AK / 2;   // bf16 1024x448
    ushort_t* obs_part = (ushort_t*)(ws + off); off += (size_t)BATCH * 512;      // bf16 Bx1024
    float* w2t = ws + off; off += 10000;
    float* w3t = ws + off; off += 1600;
    float* w1pp = ws + off; off += 384;
    ushort_t* Btg = (ushort_t*)(ws + off); off += 2304;
    float* WsampT = W_ih_T + (size_t)400 * 1024;  // rows 400..415 of W_ih_T

    prep_kernel<<<68, 256, 0, stream>>>(W_ih, W_hh, b_ih, b_hh, addr_emb,
                                        pid_emb, sid_emb, mlp_w2, mlp_w3,
                                        conv1_w, conv1_b, conv2_w,
                                        W_ih_T, Wb, bias_all, pid_rows,
                                        sid_rows, w2t, w3t, w1pp, Btg, Wobs_b);
    conv_kernel<<<BATCH, 512, 0, stream>>>(obs, w1pp, Btg, conv2_b, obs_emb_b);
    obs_gemm<<<512, 256, 0, stream>>>(obs_emb_b, Wobs_b, obs_part);
    lstm_chain<<<512, 512, 0, stream>>>(
        obs_part, bias_all, pid_rows, sid_rows,
        program_id, shape_id, shape_id_0, shape_id_1, Wb, WsampT,
        pid_ext_w, pid_ext_b, sid_ext_w, sid_ext_b, rp_ext_w, rp_ext_b,
        eps_rp, eps_rp0, eps_rp1,
        mlp_w1, mlp_b1, w2t, mlp_b2, w3t, mlp_b3, out);
}

// Round 10
// 373.294 us; speedup vs baseline: 1.3767x; 1.1128x over previous
//
#include <hip/hip_runtime.h>
#include <hip/hip_bf16.h>
#include <math.h>

#define BATCH 4096
#define HID 256
#define OUT_W 15
#define AK 448   // padded K for obs GEMM (400 valid + 48 zeros)

typedef unsigned short ushort_t;
typedef unsigned int uint_t;

using bf16x8 = __attribute__((ext_vector_type(8))) short;
using f32x4v = __attribute__((ext_vector_type(4))) float;
using f32x2 = __attribute__((ext_vector_type(2))) float;

__device__ __forceinline__ float sigf(float x) { return 1.0f / (1.0f + __expf(-x)); }
__device__ __forceinline__ float tanh_fast(float x) { return 1.0f - 2.0f / (__expf(2.0f * x) + 1.0f); }
__device__ __forceinline__ float bf2f(ushort_t u) { return __uint_as_float(((uint_t)u) << 16); }
__device__ __forceinline__ ushort_t f2bf(float x) {
    uint_t b = __float_as_uint(x);
    return (ushort_t)((b + 0x7fffu + ((b >> 16) & 1u)) >> 16);
}

// ---------------------------------------------------------------------------
// Prep (78 blocks): per-table block split (bias 7, pid 3, sid 2) to shorten
// serial loops; rest unchanged from R9.
// ---------------------------------------------------------------------------
__global__ __launch_bounds__(256) void prep_kernel(
    const float* __restrict__ W_ih, const float* __restrict__ W_hh,
    const float* __restrict__ b_ih, const float* __restrict__ b_hh,
    const float* __restrict__ addr_emb, const float* __restrict__ pid_emb,
    const float* __restrict__ sid_emb,
    const float* __restrict__ mlp_w2, const float* __restrict__ mlp_w3,
    const float* __restrict__ conv1_w, const float* __restrict__ conv1_b,
    const float* __restrict__ conv2_w,
    float* __restrict__ W_ih_T, ushort_t* __restrict__ Wb,
    float* __restrict__ bias_all, float* __restrict__ pid_rows,
    float* __restrict__ sid_rows, float* __restrict__ w2t, float* __restrict__ w3t,
    float* __restrict__ w1pp, ushort_t* __restrict__ Btg,
    ushort_t* __restrict__ Wobs_b)
{
    int blk = blockIdx.x, t = threadIdx.x;
    if (blk < 16) {
        // W_ih tile (64 cols j0, k 384..447) -> W_ih_T (WsampT source)
        __shared__ float tile[64][65];
        int j0 = blk * 64;
        int k0 = 384;
        for (int i = t; i < 4096; i += 256) {
            int r = i >> 6, c = i & 63;
            int k = k0 + c;
            tile[r][c] = (k < 432) ? W_ih[(size_t)(j0 + r) * 432 + k] : 0.f;
        }
        __syncthreads();
        for (int i = t; i < 4096; i += 256) {
            int r = i >> 6, c = i & 63;
            int k = k0 + r;
            if (k < 432) W_ih_T[(size_t)k * 1024 + j0 + c] = tile[c][r];
        }
    } else if (blk < 23) {
        const int aids[7] = {0, 1, 4, 2, 3, 5, 6};
        int s = blk - 16;
        int aid = aids[s];
        for (int j = t; j < 1024; j += 256) {
            float v = b_ih[j] + b_hh[j];
            #pragma unroll
            for (int k = 0; k < 16; k++)
                v += addr_emb[aid * 16 + k] * W_ih[(size_t)j * 432 + 416 + k];
            bias_all[s * 1024 + j] = v;
        }
    } else if (blk < 26) {
        int p = blk - 23;
        for (int j = t; j < 1024; j += 256) {
            float v = 0.f;
            #pragma unroll
            for (int k = 0; k < 16; k++)
                v += pid_emb[p * 16 + k] * W_ih[(size_t)j * 432 + 400 + k];
            pid_rows[p * 1024 + j] = v;
        }
    } else if (blk < 28) {
        int p = blk - 26;
        for (int j = t; j < 1024; j += 256) {
            float v = 0.f;
            #pragma unroll
            for (int k = 0; k < 16; k++)
                v += sid_emb[p * 16 + k] * W_ih[(size_t)j * 432 + 400 + k];
            sid_rows[p * 1024 + j] = v;
        }
    } else if (blk == 28) {
        for (int i = t; i < 10000; i += 256) {
            int o = i / 100, k = i % 100;
            w2t[k * 100 + o] = mlp_w2[i];
        }
        for (int i = t; i < 1600; i += 256) {
            int o = i / 100, k = i % 100;
            w3t[k * 16 + o] = mlp_w3[i];
        }
    } else if (blk == 29) {
        // w1pp[icq][i][k][2]: pair halves = ics (icq*8+i, icq*8+4+i)
        for (int i = t; i < 320; i += 256) {
            int half = i & 1, idx = i >> 1;
            int k = idx % 10, pr = idx / 10;
            int icq = pr >> 2, i2 = pr & 3;
            int ic = icq * 8 + i2 + half * 4;
            w1pp[i] = (k < 9) ? conv1_w[ic * 9 + k] : conv1_b[ic];
        }
        for (int i = t; i < 4608; i += 256) {
            int tap = i >> 9;
            int rem = i & 511;
            int oc = rem >> 5, ic = rem & 31;
            Btg[i] = f2bf(conv2_w[(size_t)(oc * 32 + ic) * 9 + tap]);
        }
    } else if (blk < 46) {
        int seg = blk - 30;  // 0..15
        for (int i = seg * 16384 + t; i < (seg + 1) * 16384; i += 256)
            Wb[i] = f2bf(W_hh[i]);
    } else {
        int col0 = (blk - 46) * 32;
        for (int i = t; i < 32 * AK; i += 256) {
            int c = col0 + i / AK, k = i % AK;
            Wobs_b[(size_t)c * AK + k] = (k < 400) ? f2bf(W_ih[(size_t)c * 432 + k]) : (ushort_t)0;
        }
    }
}

// ---------------------------------------------------------------------------
// Conv encoder v8 (unchanged from R9).
// ---------------------------------------------------------------------------
#define CE_RS 640
#define CO_RS 680
#define SM2S 72
#define C2S_CS 324
#define C2S_RS 20
__global__ __launch_bounds__(512, 4) void conv_kernel(
    const float* __restrict__ obs, const float* __restrict__ w1pp,
    const ushort_t* __restrict__ Btg, const float* __restrict__ b2,
    ushort_t* __restrict__ obs_emb_b)
{
    __shared__ __align__(16) ushort_t cE[17 * CE_RS];
    __shared__ __align__(16) ushort_t cO[17 * CO_RS];
    __shared__ __align__(16) float c2s[16 * C2S_CS];
    __shared__ __align__(16) float sm2[33 * SM2S];
    __shared__ __align__(16) float w1s[320];
    const int b = blockIdx.x, t = threadIdx.x;
    const float* og = obs + (size_t)b * 4096;

    const int w = t >> 6, L = t & 63, q = L >> 4, ln = L & 15;

    {
        uint_t* zE = (uint_t*)cE;
        uint_t* zO = (uint_t*)cO;
        for (int i = t; i < CE_RS / 2; i += 512) zE[i] = 0;
        for (int i = t; i < CO_RS / 2; i += 512) zO[i] = 0;
        if (t < 320) {
            int row = (t / 20) + 1, d = t % 20;
            zO[row * (CO_RS / 2) + d] = 0;
        }
    }
    if (t < 80) ((float4*)w1s)[t] = ((const float4*)w1pp)[t];
    if (t < 33) {
        int sw = (t >> 1) & 1;
        sm2[t * SM2S + sw * 4 + 3] = 0.f;
    }

    auto stage_obs = [&](int ph) {
        for (int i = t; i < 33 * 16; i += 512) {
            int row = i >> 4, c4 = i & 15;
            int sw = (row >> 1) & 1;
            int orow = 32 * ph - 1 + row;
            float4 v = float4{0.f, 0.f, 0.f, 0.f};
            if (orow >= 0) v = ((const float4*)(og + (size_t)orow * 64))[c4];
            *(float4*)&sm2[row * SM2S + ((1 + c4) ^ sw) * 4] = v;
        }
    };

    auto conv1_phase = [&](int ph) {
        const int r = t >> 5, g = (t >> 2) & 7, icq = t & 3;
        const int brow = ph ? r : (r + 1);
        float Pt[3][12];
        #pragma unroll
        for (int d = 0; d < 3; d++) {
            int row = 2 * r + d;
            int sw = (row >> 1) & 1;
            const float* base = &sm2[row * SM2S];
            #pragma unroll
            for (int j4 = 0; j4 < 3; j4++) {
                float4 v = *(const float4*)(base + ((2 * g + j4) ^ sw) * 4);
                Pt[d][j4 * 4 + 0] = v.x; Pt[d][j4 * 4 + 1] = v.y;
                Pt[d][j4 * 4 + 2] = v.z; Pt[d][j4 * 4 + 3] = v.w;
            }
        }
        const float* wpbase = &w1s[icq * 80];
        #pragma unroll
        for (int p = 0; p < 4; p++) {
            f32x2 pbc[9];
            #pragma unroll
            for (int d = 0; d < 3; d++)
                #pragma unroll
                for (int dx = 0; dx < 3; dx++) {
                    float v = Pt[d][2 * p + 3 + dx];
                    pbc[d * 3 + dx] = f32x2{v, v};
                }
            f32x2 sall[4];
            #pragma unroll
            for (int i = 0; i < 4; i++) {
                const float* wp = wpbase + i * 20;
                float4 wv0 = *(const float4*)(wp);
                float4 wv1 = *(const float4*)(wp + 4);
                float4 wv2 = *(const float4*)(wp + 8);
                float4 wv3 = *(const float4*)(wp + 12);
                float4 wv4 = *(const float4*)(wp + 16);
                f32x2 W2[10] = {f32x2{wv0.x, wv0.y}, f32x2{wv0.z, wv0.w},
                                f32x2{wv1.x, wv1.y}, f32x2{wv1.z, wv1.w},
                                f32x2{wv2.x, wv2.y}, f32x2{wv2.z, wv2.w},
                                f32x2{wv3.x, wv3.y}, f32x2{wv3.z, wv3.w},
                                f32x2{wv4.x, wv4.y}, f32x2{wv4.z, wv4.w}};
                f32x2 a2 = W2[9];
                #pragma unroll
                for (int k = 0; k < 9; k++)
                    a2 = __builtin_elementwise_fma(pbc[k], W2[k], a2);
                a2 = __builtin_elementwise_max(a2, f32x2{0.f, 0.f});
                sall[i] = a2;
            }
            uint_t d0, d1, d2, d3;
            asm("v_cvt_pk_bf16_f32 %0, %1, %2" : "=v"(d0) : "v"(sall[0].x), "v"(sall[1].x));
            asm("v_cvt_pk_bf16_f32 %0, %1, %2" : "=v"(d1) : "v"(sall[2].x), "v"(sall[3].x));
            asm("v_cvt_pk_bf16_f32 %0, %1, %2" : "=v"(d2) : "v"(sall[0].y), "v"(sall[1].y));
            asm("v_cvt_pk_bf16_f32 %0, %1, %2" : "=v"(d3) : "v"(sall[2].y), "v"(sall[3].y));
            int c = 4 * g + p;
            ushort_t* dst = (c & 1)
                ? &cO[brow * CO_RS + ((c + 1) >> 1) * 40 + icq * 8]
                : &cE[brow * CE_RS + (c >> 1) * 40 + icq * 8];
            *(uint4*)dst = uint4{d0, d1, d2, d3};
        }
    };

    auto conv2_phase = [&](int ph) {
        bf16x8 Bv[9];
        #pragma unroll
        for (int tap = 0; tap < 9; tap++)
            Bv[tap] = *reinterpret_cast<const bf16x8*>(&Btg[(tap * 16 + ln) * 32 + q * 8]);
        const int y = 8 * ph + w;
        f32x4v C = {0.f, 0.f, 0.f, 0.f};
        #pragma unroll
        for (int dy = 0; dy < 3; dy++) {
            int br = 2 * y + dy;
            if (br >= 17) br -= 17;
            bf16x8 a0 = *reinterpret_cast<const bf16x8*>(&cO[br * CO_RS + ln * 40 + q * 8]);
            bf16x8 a1 = *reinterpret_cast<const bf16x8*>(&cE[br * CE_RS + ln * 40 + q * 8]);
            bf16x8 a2 = *reinterpret_cast<const bf16x8*>(&cO[br * CO_RS + (ln + 1) * 40 + q * 8]);
            C = __builtin_amdgcn_mfma_f32_16x16x32_bf16(a0, Bv[dy * 3 + 0], C, 0, 0, 0);
            C = __builtin_amdgcn_mfma_f32_16x16x32_bf16(a1, Bv[dy * 3 + 1], C, 0, 0, 0);
            C = __builtin_amdgcn_mfma_f32_16x16x32_bf16(a2, Bv[dy * 3 + 2], C, 0, 0, 0);
        }
        float bb2 = b2[ln];
        float4 o;
        o.x = fmaxf(C[0] + bb2, 0.f);
        o.y = fmaxf(C[1] + bb2, 0.f);
        o.z = fmaxf(C[2] + bb2, 0.f);
        o.w = fmaxf(C[3] + bb2, 0.f);
        *(float4*)&c2s[ln * C2S_CS + y * C2S_RS + q * 4] = o;
    };

    stage_obs(0);
    __syncthreads();
    conv1_phase(0);
    __syncthreads();
    stage_obs(1);
    conv2_phase(0);
    __syncthreads();
    conv1_phase(1);
    __syncthreads();
    conv2_phase(1);
    __syncthreads();

    ushort_t* ew = (ushort_t*)w1s;
    if (t < 400) {
        int c = t / 25, rem = t % 25, py = rem / 5, px = rem % 5;
        float s = 0.f;
        #pragma unroll
        for (int dy = 0; dy < 3; dy++)
            #pragma unroll
            for (int dx = 0; dx < 3; dx++)
                s += c2s[c * C2S_CS + (3 * py + dy) * C2S_RS + 3 * px + dx];
        ew[t] = f2bf(s * (1.f / 9.f));
    } else if (t < AK) {
        ew[t] = 0;
    }
    __syncthreads();
    if (t < 56)
        ((uint4*)(obs_emb_b + (size_t)b * AK))[t] = ((const uint4*)ew)[t];
}

// ---------------------------------------------------------------------------
// obs_part = obs_emb_b @ Wobs_b.T (MFMA), standard [row][1024] layout.
// ---------------------------------------------------------------------------
__global__ __launch_bounds__(256) void obs_gemm(
    const ushort_t* __restrict__ Ab, const ushort_t* __restrict__ Wob,
    ushort_t* __restrict__ outp)
{
    __shared__ __align__(16) ushort_t As[64 * 72];
    __shared__ __align__(16) ushort_t ob[64 * 132];
    const int t = threadIdx.x;
    const int bm = blockIdx.x & 63, bu = blockIdx.x >> 6;
    const int b0 = bm * 64, n0 = bu * 128;
    const int w = t >> 6, L = t & 63, q = L >> 4, ln = L & 15;
    const int m0 = w * 16;

    f32x4v acc[8];
    #pragma unroll
    for (int i = 0; i < 8; i++) acc[i] = f32x4v{0.f, 0.f, 0.f, 0.f};

    for (int kc = 0; kc < 7; kc++) {
        #pragma unroll
        for (int ii = 0; ii < 2; ii++) {
            int i = t + ii * 256;
            int row = i >> 3, c8 = i & 7;
            *(uint4*)&As[row * 72 + c8 * 8] =
                *(const uint4*)&Ab[(size_t)(b0 + row) * AK + kc * 64 + c8 * 8];
        }
        __syncthreads();
        bf16x8 a[2];
        #pragma unroll
        for (int ks = 0; ks < 2; ks++)
            a[ks] = *reinterpret_cast<const bf16x8*>(&As[(m0 + ln) * 72 + ks * 32 + q * 8]);
        #pragma unroll
        for (int ct = 0; ct < 8; ct++) {
            const ushort_t* wr = Wob + (size_t)(n0 + ct * 16 + ln) * AK + kc * 64 + q * 8;
            bf16x8 bv0 = *reinterpret_cast<const bf16x8*>(wr);
            bf16x8 bv1 = *reinterpret_cast<const bf16x8*>(wr + 32);
            acc[ct] = __builtin_amdgcn_mfma_f32_16x16x32_bf16(a[0], bv0, acc[ct], 0, 0, 0);
            acc[ct] = __builtin_amdgcn_mfma_f32_16x16x32_bf16(a[1], bv1, acc[ct], 0, 0, 0);
        }
        __syncthreads();
    }
    #pragma unroll
    for (int ct = 0; ct < 8; ct++)
        #pragma unroll
        for (int j = 0; j < 4; j++)
            ob[(m0 + q * 4 + j) * 132 + ct * 16 + ln] = f2bf(acc[ct][j]);
    __syncthreads();
    #pragma unroll
    for (int p2 = 0; p2 < 4; p2++) {
        int idx = t + p2 * 256;
        int row = idx >> 4, c8 = idx & 15;
        uint4 v = *(const uint4*)&ob[row * 132 + c8 * 8];
        *(uint4*)&outp[(size_t)(b0 + row) * 1024 + n0 + c8 * 8] = v;
    }
}

// ---------------------------------------------------------------------------
// LSTM chain v4: R7 geometry (256 blocks x 16 rows, 512 thr, (512,2) ->
// 256 VGPR cap, no spill) with the stall sources removed:
//   - GEMM B-operands explicitly DOUBLE-BUFFER PREFETCHED (8 loads in
//     flight) instead of just-in-time per MFMA (R9's 64-VGPR frame
//     serialized every B-load at ~300cy L2 latency).
//   - obs_part staged coalesced [row][1032] (no transpose conflicts).
//   - all 6 pre-rp1 heads in ONE barrier-free butterfly phase
//     (half-wave per row), replacing 6 calls x 2 barriers.
// GEMMs: g(h0)[s1+s1b], g(h1)[s2], g(h1b)[s2b], g(h2b)[s3b], g(h3b)[s4b].
// bufs: 0=h0(->h4b), 1=h1, 2=h1b, 3=h2, 4=h2b, 5=h3b.
// ---------------------------------------------------------------------------
#define HLS 264   // hline row stride (ushorts)
__global__ __launch_bounds__(512, 2) void lstm_chain(
    const ushort_t* __restrict__ obs_part, const float* __restrict__ bias_all,
    const float* __restrict__ pid_rows, const float* __restrict__ sid_rows,
    const int* __restrict__ program_id, const int* __restrict__ shape_id,
    const int* __restrict__ shape_id_0, const int* __restrict__ shape_id_1,
    const ushort_t* __restrict__ Wb, const float* __restrict__ WsampT,
    const float* __restrict__ pid_ext_w, const float* __restrict__ pid_ext_b,
    const float* __restrict__ sid_ext_w, const float* __restrict__ sid_ext_b,
    const float* __restrict__ rp_ext_w, const float* __restrict__ rp_ext_b,
    const float* __restrict__ eps_rp, const float* __restrict__ eps_rp0,
    const float* __restrict__ eps_rp1,
    const float* __restrict__ mlp_w1, const float* __restrict__ mlp_b1,
    const float* __restrict__ w2t, const float* __restrict__ mlp_b2,
    const float* __restrict__ w3t, const float* __restrict__ mlp_b3,
    float* __restrict__ out)
{
    __shared__ __align__(16) ushort_t hline[6][16 * HLS];  // 50688 B
    __shared__ __align__(16) ushort_t ps[16 * 1032];       // 33024 B
    __shared__ float z1s[16][102], z2s[16][102];           // 13056 B
    __shared__ float emb_s[16][20];                        // 1280 B
    __shared__ float rp0s[16][2];
    __shared__ int sidx_s[4][16];

    const int t = threadIdx.x;
    const int b0 = blockIdx.x * 16;
    const int w = t >> 6, l = t & 63, q = l >> 4, ln = l & 15;
    const int U = w * 32;

    if (t < 64) {
        int tbl = t >> 4, r = t & 15;
        const int* src = (tbl == 0) ? program_id : (tbl == 1) ? shape_id
                       : (tbl == 2) ? shape_id_0 : shape_id_1;
        sidx_s[tbl][r] = src[b0 + r];
    }
    // stage obs_part slice (16 rows x 1024 bf16), coalesced
    for (int i = t; i < 2048; i += 512) {
        int r = i >> 7, c8 = i & 127;
        uint4 v = *(const uint4*)&obs_part[(size_t)(b0 + r) * 1024 + c8 * 8];
        *(uint4*)&ps[r * 1032 + c8 * 8] = v;
    }
    __syncthreads();

    float cA[8], cB[8];      // cell state [j*2+h]
    f32x4v acc[4][2];        // gemm result [gate][h]

    // ---- s0 (bias 0): h=c=0 -> h0 (buf0), cA=cB=c0
    #pragma unroll
    for (int h = 0; h < 2; h++) {
        const int unit = U + h * 16 + ln;
        #pragma unroll
        for (int j = 0; j < 4; j++) {
            int row = q * 4 + j;
            float pre[4];
            #pragma unroll
            for (int g = 0; g < 4; g++) {
                int col = g * 256 + unit;
                pre[g] = bf2f(ps[row * 1032 + col]) + bias_all[col];
            }
            float c2 = sigf(pre[0]) * tanh_fast(pre[2]);
            float hv = sigf(pre[3]) * tanh_fast(c2);
            cA[j * 2 + h] = c2; cB[j * 2 + h] = c2;
            hline[0][row * HLS + unit] = f2bf(hv);
        }
    }
    __syncthreads();

    // GEMM with explicit double-buffered B prefetch (8 loads in flight)
    auto gemm = [&](int src) {
        bf16x8 a[8];
        #pragma unroll
        for (int kk = 0; kk < 8; kk++)
            a[kk] = *reinterpret_cast<const bf16x8*>(
                &hline[src][ln * HLS + kk * 32 + q * 8]);
        bf16x8 bva[8], bvb[8];
        auto loadB = [&](bf16x8* dst, int grp) {
            const int g = grp >> 1, h = grp & 1;
            const ushort_t* wr = Wb + (size_t)(g * 256 + U + h * 16 + ln) * 256 + q * 8;
            #pragma unroll
            for (int kk = 0; kk < 8; kk++)
                dst[kk] = *reinterpret_cast<const bf16x8*>(wr + kk * 32);
        };
        auto mmaB = [&](const bf16x8* bv, int grp) {
            f32x4v z = {0.f, 0.f, 0.f, 0.f};
            #pragma unroll
            for (int kk = 0; kk < 8; kk++)
                z = __builtin_amdgcn_mfma_f32_16x16x32_bf16(a[kk], bv[kk], z, 0, 0, 0);
            acc[grp >> 1][grp & 1] = z;
        };
        loadB(bva, 0);
        loadB(bvb, 1); mmaB(bva, 0);
        loadB(bva, 2); mmaB(bvb, 1);
        loadB(bvb, 3); mmaB(bva, 2);
        loadB(bva, 4); mmaB(bvb, 3);
        loadB(bvb, 5); mmaB(bva, 4);
        loadB(bva, 6); mmaB(bvb, 5);
        loadB(bvb, 7); mmaB(bva, 6);
        mmaB(bvb, 7);
    };

    auto epi = [&](int bi, const float* samp, int tbl, int dst, bool useA) {
        #pragma unroll
        for (int h = 0; h < 2; h++) {
            const int unit = U + h * 16 + ln;
            #pragma unroll
            for (int j = 0; j < 4; j++) {
                int row = q * 4 + j;
                int si = sidx_s[tbl][row];
                float pre[4];
                #pragma unroll
                for (int g = 0; g < 4; g++) {
                    int col = g * 256 + unit;
                    pre[g] = acc[g][h][j] + bf2f(ps[row * 1032 + col])
                           + bias_all[bi * 1024 + col]
                           + samp[(size_t)si * 1024 + col];
                }
                float ci = useA ? cA[j * 2 + h] : cB[j * 2 + h];
                float c2 = sigf(pre[1]) * ci + sigf(pre[0]) * tanh_fast(pre[2]);
                float hv = sigf(pre[3]) * tanh_fast(c2);
                if (useA) cA[j * 2 + h] = c2; else cB[j * 2 + h] = c2;
                hline[dst][row * HLS + unit] = f2bf(hv);
            }
        }
    };

    // phase A: s1 (bias1) + s1b (bias3) share gemm(h0)
    gemm(0);
    epi(1, pid_rows, 0, 1, true);    // h1 -> buf1
    epi(3, pid_rows, 0, 2, false);   // h1b -> buf2
    __syncthreads();
    // phase B: s2 and s2b (independent)
    gemm(1);
    epi(2, sid_rows, 1, 3, true);    // h2 -> buf3
    gemm(2);
    epi(4, sid_rows, 2, 4, false);   // h2b -> buf4
    __syncthreads();
    // phase C: s3b
    gemm(4);
    epi(5, sid_rows, 3, 5, false);   // h3b -> buf5
    __syncthreads();

    // ---- batched heads: half-wave per row; 17 dots; 5-step butterfly
    {
        const int half = l >> 5, sl = l & 31;
        const int r = w + half * 8, R = b0 + r, d0 = sl * 8;
        float hv8[8];
        auto ldh = [&](int buf) {
            uint4 v = *(const uint4*)&hline[buf][r * HLS + d0];
            uint_t dw[4] = {v.x, v.y, v.z, v.w};
            #pragma unroll
            for (int k2 = 0; k2 < 4; k2++) {
                hv8[k2 * 2]     = bf2f((ushort_t)(dw[k2] & 0xffffu));
                hv8[k2 * 2 + 1] = bf2f((ushort_t)(dw[k2] >> 16));
            }
        };
        auto dot = [&](const float* wrow) {
            float4 wa = *(const float4*)&wrow[d0];
            float4 wb = *(const float4*)&wrow[d0 + 4];
            return hv8[0] * wa.x + hv8[1] * wa.y + hv8[2] * wa.z + hv8[3] * wa.w
                 + hv8[4] * wb.x + hv8[5] * wb.y + hv8[6] * wb.z + hv8[7] * wb.w;
        };
        float part[17];
        ldh(0);                                  // h0 -> pid (0..2)
        part[0] = dot(pid_ext_w);
        part[1] = dot(pid_ext_w + 256);
        part[2] = dot(pid_ext_w + 512);
        ldh(1);                                  // h1 -> sid (3..4)
        part[3] = dot(sid_ext_w);
        part[4] = dot(sid_ext_w + 256);
        ldh(2);                                  // h1b -> sid0 (9..10)
        part[9]  = dot(sid_ext_w);
        part[10] = dot(sid_ext_w + 256);
        ldh(4);                                  // h2b -> sid1 (11..12)
        part[11] = dot(sid_ext_w);
        part[12] = dot(sid_ext_w + 256);
        ldh(3);                                  // h2 -> rp_b0 (5..8)
        part[5] = dot(rp_ext_w);
        part[6] = dot(rp_ext_w + 256);
        part[7] = dot(rp_ext_w + 512);
        part[8] = dot(rp_ext_w + 768);
        ldh(5);                                  // h3b -> rp0 (13..16)
        part[13] = dot(rp_ext_w);
        part[14] = dot(rp_ext_w + 256);
        part[15] = dot(rp_ext_w + 512);
        part[16] = dot(rp_ext_w + 768);
        #pragma unroll
        for (int m = 0; m < 17; m++) {
            float s = part[m];
            s += __shfl_xor(s, 1);  s += __shfl_xor(s, 2);  s += __shfl_xor(s, 4);
            s += __shfl_xor(s, 8);  s += __shfl_xor(s, 16);
            part[m] = s;
        }
        if (sl == 0) {
            float* orow = out + (size_t)R * OUT_W;
            orow[0] = part[0] + pid_ext_b[0];
            orow[1] = part[1] + pid_ext_b[1];
            orow[2] = part[2] + pid_ext_b[2];
            orow[3] = part[3] + sid_ext_b[0];
            orow[4] = part[4] + sid_ext_b[1];
            float s0 = part[5] + rp_ext_b[0], s1 = part[6] + rp_ext_b[1];
            float s2 = part[7] + rp_ext_b[2], s3 = part[8] + rp_ext_b[3];
            orow[5] = s0 + __expf(s2) * eps_rp[(size_t)R * 2 + 0];
            orow[6] = s1 + __expf(s3) * eps_rp[(size_t)R * 2 + 1];
            orow[7]  = part[9]  + sid_ext_b[0];
            orow[8]  = part[10] + sid_ext_b[1];
            orow[9]  = part[11] + sid_ext_b[0];
            orow[10] = part[12] + sid_ext_b[1];
            float t0 = part[13] + rp_ext_b[0], t1 = part[14] + rp_ext_b[1];
            float t2 = part[15] + rp_ext_b[2], t3 = part[16] + rp_ext_b[3];
            float v0 = t0 + __expf(t2) * eps_rp0[(size_t)R * 2 + 0];
            float v1 = t1 + __expf(t3) * eps_rp0[(size_t)R * 2 + 1];
            orow[11] = v0; orow[12] = v1;
            rp0s[r][0] = v0; rp0s[r][1] = v1;
        }
    }
    __syncthreads();

    // ---- MLP: rp0 -> 100 -> 100 -> emb (16 rows)
    for (int i = t; i < 1600; i += 512) {
        int row = i / 100, j2 = i % 100;
        z1s[row][j2] = tanh_fast(mlp_b1[j2] + mlp_w1[j2 * 2] * rp0s[row][0]
                                            + mlp_w1[j2 * 2 + 1] * rp0s[row][1]);
    }
    __syncthreads();
    for (int i = t; i < 1600; i += 512) {
        int row = i / 100, j2 = i % 100;
        float s = mlp_b2[j2];
        for (int k = 0; k < 100; k++) s += w2t[k * 100 + j2] * z1s[row][k];
        z2s[row][j2] = tanh_fast(s);
    }
    __syncthreads();
    if (t < 256) {
        int row = t >> 4, o = t & 15;
        float s = mlp_b3[o];
        for (int k = 0; k < 100; k++) s += w3t[k * 16 + o] * z2s[row][k];
        emb_s[row][o] = s;
    }
    __syncthreads();

    // ---- s4b (bias6, samp = emb @ WsampT): h3b -> h4b (buf0)
    gemm(5);
    #pragma unroll
    for (int h = 0; h < 2; h++) {
        const int unit = U + h * 16 + ln;
        float pre[4][4];
        #pragma unroll
        for (int j = 0; j < 4; j++) {
            int row = q * 4 + j;
            #pragma unroll
            for (int g = 0; g < 4; g++) {
                int col = g * 256 + unit;
                pre[g][j] = acc[g][h][j] + bf2f(ps[row * 1032 + col])
                          + bias_all[6 * 1024 + col];
            }
        }
        #pragma unroll
        for (int k = 0; k < 16; k++) {
            float wv[4];
            #pragma unroll
            for (int g = 0; g < 4; g++)
                wv[g] = WsampT[(size_t)k * 1024 + g * 256 + unit];
            #pragma unroll
            for (int j = 0; j < 4; j++) {
                float e = emb_s[q * 4 + j][k];
                #pragma unroll
                for (int g = 0; g < 4; g++) pre[g][j] += e * wv[g];
            }
        }
        #pragma unroll
        for (int j = 0; j < 4; j++) {
            float c2 = sigf(pre[1][j]) * cB[j * 2 + h]
                     + sigf(pre[0][j]) * tanh_fast(pre[2][j]);
            float hv = sigf(pre[3][j]) * tanh_fast(c2);
            hline[0][(q * 4 + j) * HLS + unit] = f2bf(hv);
        }
    }
    __syncthreads();

    // ---- rp1 head on h4b (buf0), butterfly
    {
        const int half = l >> 5, sl = l & 31;
        const int r = w + half * 8, R = b0 + r, d0 = sl * 8;
        float hv8[8];
        uint4 v = *(const uint4*)&hline[0][r * HLS + d0];
        uint_t dw[4] = {v.x, v.y, v.z, v.w};
        #pragma unroll
        for (int k2 = 0; k2 < 4; k2++) {
            hv8[k2 * 2]     = bf2f((ushort_t)(dw[k2] & 0xffffu));
            hv8[k2 * 2 + 1] = bf2f((ushort_t)(dw[k2] >> 16));
        }
        float p[4];
        #pragma unroll
        for (int m = 0; m < 4; m++) {
            const float* wrow = rp_ext_w + m * 256;
            float4 wa = *(const float4*)&wrow[d0];
            float4 wb = *(const float4*)&wrow[d0 + 4];
            p[m] = hv8[0] * wa.x + hv8[1] * wa.y + hv8[2] * wa.z + hv8[3] * wa.w
                 + hv8[4] * wb.x + hv8[5] * wb.y + hv8[6] * wb.z + hv8[7] * wb.w;
        }
        #pragma unroll
        for (int m = 0; m < 4; m++) {
            float s = p[m];
            s += __shfl_xor(s, 1);  s += __shfl_xor(s, 2);  s += __shfl_xor(s, 4);
            s += __shfl_xor(s, 8);  s += __shfl_xor(s, 16);
            p[m] = s;
        }
        if (sl == 0) {
            float s0 = p[0] + rp_ext_b[0], s1 = p[1] + rp_ext_b[1];
            float s2 = p[2] + rp_ext_b[2], s3 = p[3] + rp_ext_b[3];
            out[(size_t)R * OUT_W + 13] = s0 + __expf(s2) * eps_rp1[(size_t)R * 2 + 0];
            out[(size_t)R * OUT_W + 14] = s1 + __expf(s3) * eps_rp1[(size_t)R * 2 + 1];
        }
    }
}

// ---------------------------------------------------------------------------
extern "C" void kernel_launch(void* const* d_in, const int* in_sizes, int n_in,
                              void* d_out, int out_size, void* d_ws, size_t ws_size,
                              hipStream_t stream)
{
    const float* obs        = (const float*)d_in[0];
    const int*   program_id = (const int*)d_in[1];
    const int*   shape_id   = (const int*)d_in[2];
    const int*   shape_id_0 = (const int*)d_in[3];
    const int*   shape_id_1 = (const int*)d_in[4];
    const float* eps_rp     = (const float*)d_in[5];
    const float* eps_rp0    = (const float*)d_in[6];
    const float* eps_rp1    = (const float*)d_in[7];
    const float* conv1_w    = (const float*)d_in[8];
    const float* conv1_b    = (const float*)d_in[9];
    const float* conv2_w    = (const float*)d_in[10];
    const float* conv2_b    = (const float*)d_in[11];
    const float* mlp_w1     = (const float*)d_in[12];
    const float* mlp_b1     = (const float*)d_in[13];
    const float* mlp_w2     = (const float*)d_in[14];
    const float* mlp_b2     = (const float*)d_in[15];
    const float* mlp_w3     = (const float*)d_in[16];
    const float* mlp_b3     = (const float*)d_in[17];
    const float* W_ih       = (const float*)d_in[18];
    const float* b_ih       = (const float*)d_in[19];
    const float* W_hh       = (const float*)d_in[20];
    const float* b_hh       = (const float*)d_in[21];
    const float* addr_emb   = (const float*)d_in[22];
    const float* pid_emb    = (const float*)d_in[23];
    const float* sid_emb    = (const float*)d_in[24];
    const float* pid_ext_w  = (const float*)d_in[25];
    const float* pid_ext_b  = (const float*)d_in[26];
    const float* sid_ext_w  = (const float*)d_in[27];
    const float* sid_ext_b  = (const float*)d_in[28];
    const float* rp_ext_w   = (const float*)d_in[29];
    const float* rp_ext_b   = (const float*)d_in[30];
    float* out = (float*)d_out;

    // workspace layout
    float* ws = (float*)d_ws;
    size_t off = 0;
    float* W_ih_T   = ws + off; off += 432 * 1024;              // fp32 (WsampT source)
    ushort_t* Wb    = (ushort_t*)(ws + off); off += 131072;     // bf16 1024x256
    float* bias_all = ws + off; off += 7 * 1024;
    float* pid_rows = ws + off; off += 3 * 1024;
    float* sid_rows = ws + off; off += 2 * 1024;
    ushort_t* obs_emb_b = (ushort_t*)(ws + off); off += (size_t)BATCH * AK / 2;  // bf16 Bx448
    ushort_t* Wobs_b    = (ushort_t*)(ws + off); off += (size_t)1024 * AK / 2;   // bf16 1024x448
    ushort_t* obs_part = (ushort_t*)(ws + off); off += (size_t)BATCH * 512;      // bf16 Bx1024
    float* w2t = ws + off; off += 10000;
    float* w3t = ws + off; off += 1600;
    float* w1pp = ws + off; off += 384;
    ushort_t* Btg = (ushort_t*)(ws + off); off += 2304;
    float* WsampT = W_ih_T + (size_t)400 * 1024;  // rows 400..415 of W_ih_T

    prep_kernel<<<78, 256, 0, stream>>>(W_ih, W_hh, b_ih, b_hh, addr_emb,
                                        pid_emb, sid_emb, mlp_w2, mlp_w3,
                                        conv1_w, conv1_b, conv2_w,
                                        W_ih_T, Wb, bias_all, pid_rows,
                                        sid_rows, w2t, w3t, w1pp, Btg, Wobs_b);
    conv_kernel<<<BATCH, 512, 0, stream>>>(obs, w1pp, Btg, conv2_b, obs_emb_b);
    obs_gemm<<<512, 256, 0, stream>>>(obs_emb_b, Wobs_b, obs_part);
    lstm_chain<<<256, 512, 0, stream>>>(
        obs_part, bias_all, pid_rows, sid_rows,
        program_id, shape_id, shape_id_0, shape_id_1, Wb, WsampT,
        pid_ext_w, pid_ext_b, sid_ext_w, sid_ext_b, rp_ext_w, rp_ext_b,
        eps_rp, eps_rp0, eps_rp1,
        mlp_w1, mlp_b1, w2t, mlp_b2, w3t, mlp_b3, out);
}